// Round 1
// baseline (2190.386 us; speedup 1.0000x reference)
//
#include <hip/hip_runtime.h>
#include <hip/hip_bf16.h>

// ---------------------------------------------------------------------------
// SpecGCN + 2-layer LSTM (encoder 28 steps, decoder 7 steps) + FC, eval mode.
// B=256 D=28 N=23 F=128 O=64 H=128 Y=7. f32 everywhere (correctness round).
//
// Pipeline:
//   kernPrep: pack LSTM weights into coalesced [k4][512]x float4 layout,
//             transpose gcn_w -> gwt [O][F].
//   kernA   : one block per (b,d): GraphLearner -> adj (output 0) -> SpecGCN
//             -> writes zin [D][NB][65] into workspace.
//   kernB   : one block per 23 sequences (grid=256 = 1 block/CU). Both LSTM
//             layers fused; h in LDS, c in registers; per-thread owns one
//             channel j of all 4 gates for a 6-sequence subset -> no gate
//             LDS round trip. Decoder + FC fused, writes y (output 1).
// ---------------------------------------------------------------------------

#define DB 256
#define DD 28
#define DN 23
#define DF 128
#define DO 64
#define DH 128
#define DY 7
#define DC 65                      // O+1
#define NBSEQ (DN*DB)              // 5888
#define ADJSZ (DB*DD*DN*DN)        // 3,791,872

// workspace float offsets
#define ZIN_OFF 0
#define ZIN_SZ  (DD*NBSEQ*DC)      // 10,716,160
#define WC0_OFF (ZIN_OFF + ZIN_SZ)
#define WC0_SZ  (512*49*4)         // 100,352  (rows padded 193->196)
#define WC1_OFF (WC0_OFF + WC0_SZ)
#define WC1_SZ  (512*65*4)         // 133,120  (rows padded 256->260)
#define GWT_OFF (WC1_OFF + WC1_SZ)
#define GWT_SZ  (DO*DF)            // 8192

__device__ __forceinline__ float fsig(float x)  { return 1.f/(1.f+__expf(-x)); }
__device__ __forceinline__ float ftanh(float x) { return 1.f - 2.f/(__expf(2.f*x)+1.f); }

#define FMA4(xv, wv, a) fmaf((xv).w,(wv).w, fmaf((xv).z,(wv).z, fmaf((xv).y,(wv).y, fmaf((xv).x,(wv).x,(a)))))

// ---------------------------------------------------------------------------
// Prep: pack lstm weights + transpose gcn_w
// wc0 float idx = 4*(k4*512 + r) + c ; combined row r = [wih0(65)|whh0(128)|0pad]
// wc1 combined row r = [wih1(128)|whh1(128)|0pad]
// ---------------------------------------------------------------------------
__global__ __launch_bounds__(256) void kernPrep(
    const float* __restrict__ wih0, const float* __restrict__ whh0,
    const float* __restrict__ wih1, const float* __restrict__ whh1,
    const float* __restrict__ gcn_w,
    float* __restrict__ wc0, float* __restrict__ wc1, float* __restrict__ gwt)
{
    int idx = blockIdx.x*256 + threadIdx.x;
    if (idx < 512*196) {
        int c = idx & 3; int rk = idx >> 2; int r = rk & 511; int k4 = rk >> 9;
        int col = k4*4 + c;
        float v = 0.f;
        if (col < 65)       v = wih0[r*65 + col];
        else if (col < 193) v = whh0[r*128 + (col-65)];
        wc0[idx] = v;
        return;
    }
    idx -= 512*196;
    if (idx < 512*260) {
        int c = idx & 3; int rk = idx >> 2; int r = rk & 511; int k4 = rk >> 9;
        int col = k4*4 + c;
        float v = 0.f;
        if (col < 128)      v = wih1[r*128 + col];
        else if (col < 256) v = whh1[r*128 + (col-128)];
        wc1[idx] = v;
        return;
    }
    idx -= 512*260;
    if (idx < DO*DF) {
        int o = idx >> 7, f = idx & 127;
        gwt[idx] = gcn_w[f*DO + o];     // gwt[o][f]
    }
}

// ---------------------------------------------------------------------------
// Kernel A: per-(b,d) graph stage.  grid = B*D = 7168, block = 256.
// LDS ~47 KB -> 3 blocks/CU.
// ---------------------------------------------------------------------------
__global__ __launch_bounds__(256) void kernA(
    const float* __restrict__ x, const float* __restrict__ adj_real,
    const float* __restrict__ infection, const int* __restrict__ day_order,
    const float* __restrict__ w1, const float* __restrict__ b1,
    const float* __restrict__ w2, const float* __restrict__ b2,
    const float* __restrict__ glp, const float* __restrict__ vvec,
    const float* __restrict__ gwt,
    float* __restrict__ out_adj, float* __restrict__ zin)
{
    const int bd = blockIdx.x;
    const int b  = bd / DD;
    const int d  = bd - b*DD;
    const int t  = threadIdx.x;

    __shared__ float sm[11753];
    const int XS=0, N1=3036, N2=6072, S12=9108, ADJ=9660, XW=10212,
              DEG=11684, DINV=11707, FACT=11730;
    const int XWP = N1;   // alias: n1/n2 dead after s12 phase (needs 5888 <= 6072)

    // --- A1: stage x tile [23][128] (row pad 132), day factor
    const float* xg = x + (size_t)bd * (DN*DF);
    for (int p = t; p < DN*DF; p += 256) {
        int n = p >> 7, f = p & 127;
        sm[XS + n*132 + f] = xg[p];
    }
    if (t < DN) {
        float vv = vvec[t];
        sm[FACT + t] = __expf(vv*vv*(float)day_order[b]);
    }
    __syncthreads();

    // --- A2: n1 = tanh(x@w1^T + b1), n2 = tanh(x@w2^T + b2)
    {
        const int mat = t >> 7, fo = t & 127;
        const float* wr = (mat ? w2 : w1) + fo*DF;
        const float bias = (mat ? b2 : b1)[fo];
        float acc[DN];
        #pragma unroll
        for (int n=0;n<DN;n++) acc[n]=0.f;
        float4 w4 = *(const float4*)wr;
        for (int k4=0;k4<32;k4++){
            float4 wn = w4;
            if (k4 < 31) wn = *(const float4*)(wr + 4*(k4+1));
            #pragma unroll
            for (int n=0;n<DN;n++){
                float4 xv = *(const float4*)&sm[XS + n*132 + 4*k4];
                acc[n] = FMA4(xv, w4, acc[n]);
            }
            w4 = wn;
        }
        const int dst = mat ? N2 : N1;
        #pragma unroll
        for (int n=0;n<DN;n++) sm[dst + n*132 + fo] = ftanh(acc[n]+bias);
    }
    __syncthreads();

    // --- A3: s12[i][j] = n1[i].n2[j]; deg[n] = rowsum(adj_real)
    if (t < DN) {
        const float* ar = adj_real + (size_t)bd*(DN*DN) + t*DN;
        float s = 0.f;
        for (int m=0;m<DN;m++) s += ar[m];
        sm[DEG+t] = s;
    }
    for (int p=t; p<DN*DN; p+=256){
        int i = p/DN, j = p - i*DN;
        float a = 0.f;
        for (int k4=0;k4<32;k4++){
            float4 av = *(const float4*)&sm[N1 + i*132 + 4*k4];
            float4 bv = *(const float4*)&sm[N2 + j*132 + 4*k4];
            a = FMA4(av, bv, a);
        }
        sm[S12 + i*24 + j] = a;
    }
    __syncthreads();

    // --- A4: adj = relu(tanh(s12 - s12^T)) + sigmoid(glp*deg_i*deg_j)*adj_real
    for (int p=t; p<DN*DN; p+=256){
        int i=p/DN, j=p-i*DN;
        float al  = fmaxf(ftanh(sm[S12+i*24+j]-sm[S12+j*24+i]), 0.f);
        float md  = fsig(glp[i*DN+j]*sm[DEG+i]*sm[DEG+j]);
        float arv = adj_real[(size_t)bd*(DN*DN) + p];
        float adjv = al + md*arv;
        out_adj[(size_t)bd*(DN*DN) + p] = adjv;
        sm[ADJ + i*24 + j] = adjv + (i==j ? 1.f : 0.f);   // tA = adj + I
    }
    __syncthreads();

    // --- A5: dinv = rowsum(tA)^-1/2
    if (t<DN){
        float rs=0.f;
        for (int jj=0;jj<DN;jj++) rs += sm[ADJ+t*24+jj];
        sm[DINV+t] = rsqrtf(rs);
    }
    __syncthreads();

    // --- A6: dad in place
    for (int p=t;p<DN*DN;p+=256){
        int i=p/DN, j=p-i*DN;
        sm[ADJ+i*24+j] *= sm[DINV+i]*sm[DINV+j];
    }
    __syncthreads();

    // --- A7: xw = x @ gcn_w  (k split 4 ways, partials in XWP alias)
    {
        const int o = t & 63, q = t >> 6;
        float acc[DN];
        #pragma unroll
        for (int n=0;n<DN;n++) acc[n]=0.f;
        const float* gw = gwt + o*DF + q*32;
        for (int k4=0;k4<8;k4++){
            float4 w4 = *(const float4*)(gw + 4*k4);
            #pragma unroll
            for (int n=0;n<DN;n++){
                float4 xv = *(const float4*)&sm[XS + n*132 + q*32 + 4*k4];
                acc[n] = FMA4(xv, w4, acc[n]);
            }
        }
        #pragma unroll
        for (int n=0;n<DN;n++) sm[XWP + (q*DN+n)*64 + o] = acc[n];
    }
    __syncthreads();
    for (int p=t;p<DN*64;p+=256){
        int n=p>>6, o=p&63;
        sm[XW+p] = sm[XWP + n*64 + o] + sm[XWP + (DN+n)*64 + o]
                 + sm[XWP + (2*DN+n)*64 + o] + sm[XWP + (3*DN+n)*64 + o];
    }
    __syncthreads();

    // --- A8: gcn = relu(dad @ xw) * factor -> zin[d][n*256+b][o]; infection at c=64
    for (int p=t;p<DN*64;p+=256){
        int n=p>>6, o=p&63;
        float a=0.f;
        #pragma unroll
        for (int m=0;m<DN;m++) a = fmaf(sm[ADJ+n*24+m], sm[XW+m*64+o], a);
        a = fmaxf(a,0.f)*sm[FACT+n];
        zin[((size_t)d*NBSEQ + n*DB + b)*DC + o] = a;
    }
    if (t<DN)
        zin[((size_t)d*NBSEQ + t*DB + b)*DC + 64] = infection[(size_t)bd*DN + t];
}

// ---------------------------------------------------------------------------
// Kernel B: fused 2-layer LSTM (28 enc + 7 dec steps) + FC.
// grid = 256 (1 block/CU), block = 512.  23 sequences/block (+1 dummy row).
// Thread t: channel j = t&127 of all 4 gates, sequence subset sg = t>>7 (6 rows).
// c-states in registers, h-states in LDS.  LDS ~50 KB.
// ---------------------------------------------------------------------------
__global__ __launch_bounds__(512) void kernB(
    const float* __restrict__ zin, const float* __restrict__ wc0,
    const float* __restrict__ wc1, const float* __restrict__ b0g,
    const float* __restrict__ b1g, const float* __restrict__ infection,
    const float* __restrict__ fcw, const float* __restrict__ fcb,
    float* __restrict__ outy)
{
    const int t  = threadIdx.x;
    const int s0 = blockIdx.x * DN;

    __shared__ float sm[12619];
    const int IN0=0;        // 24 rows x 196 : [x(65) | h0(128) | pad]
    const int IN1=4704;     // 24 rows x 260 : [h0(128) | h1(128) | pad]
    const int X2 =10944;    // 23 x 65 running sum of inputs
    const int FCW=12439;    // 156 fc weights + fc bias
    const int INFC=12596;   // 23 precomputed infection dot

    const int j  = t & 127;
    const int sg = t >> 7;
    const int sbase = sg * 6;          // group 3 covers s=18..23 (23 = dummy)

    for (int p=t;p<12439;p+=512) sm[p]=0.f;
    if (t<157) sm[FCW+t] = (t<156)? fcw[t] : fcb[0];
    if (t<DN){
        int sgl = s0 + t; int bb = sgl & 255; int nn = sgl >> 8;
        float a=0.f;
        for (int dd=0; dd<DD; dd++)
            a = fmaf(fcw[DH+dd], infection[((size_t)bb*DD+dd)*DN+nn], a);
        sm[INFC+t] = a;
    }
    float bias0[4], bias1[4], c0r[6], c1r[6];
    #pragma unroll
    for (int g=0; g<4; g++){ bias0[g]=b0g[g*128+j]; bias1[g]=b1g[g*128+j]; }
    #pragma unroll
    for (int n=0;n<6;n++){ c0r[n]=0.f; c1r[n]=0.f; }
    __syncthreads();

    const float4* w0p  = (const float4*)wc0;
    const float4* w1p  = (const float4*)wc1;
    const float4* in0f = (const float4*)&sm[IN0];
    const float4* in1f = (const float4*)&sm[IN1];

    for (int step=0; step<DD+DY; ++step){
        if (step < DD){
            const float* zp = zin + ((size_t)step*NBSEQ + s0)*DC;
            for (int q=t; q<DN*DC; q+=512){
                float vv = zp[q];
                int s = q/DC, c = q - s*DC;
                sm[IN0 + s*196 + c] = vv;
                sm[X2 + q] += vv;
            }
        } else if (step == DD){
            for (int q=t;q<DN*DC;q+=512){
                int s=q/DC, c=q-s*DC;
                sm[IN0 + s*196 + c] = sm[X2+q]*(1.f/(float)DD);
            }
        }
        __syncthreads();

        // ---------- layer 0 : gates over [x | h0], K=193 (49 float4) ----------
        {
            float acc[6][4];
            #pragma unroll
            for (int n=0;n<6;n++){
                #pragma unroll
                for (int g=0;g<4;g++) acc[n][g] = bias0[g];
            }
            float4 wA0 = w0p[j], wA1 = w0p[128+j], wA2 = w0p[256+j], wA3 = w0p[384+j];
            for (int k4=0;k4<49;k4++){
                float4 wB0=wA0, wB1=wA1, wB2=wA2, wB3=wA3;
                if (k4 < 48){
                    const float4* nxt = w0p + (size_t)(k4+1)*512 + j;
                    wB0 = nxt[0]; wB1 = nxt[128]; wB2 = nxt[256]; wB3 = nxt[384];
                }
                #pragma unroll
                for (int n=0;n<6;n++){
                    float4 xv = in0f[(sbase+n)*49 + k4];
                    acc[n][0] = FMA4(xv, wA0, acc[n][0]);
                    acc[n][1] = FMA4(xv, wA1, acc[n][1]);
                    acc[n][2] = FMA4(xv, wA2, acc[n][2]);
                    acc[n][3] = FMA4(xv, wA3, acc[n][3]);
                }
                wA0=wB0; wA1=wB1; wA2=wB2; wA3=wB3;
            }
            __syncthreads();           // all dots done before h0 overwritten
            #pragma unroll
            for (int n=0;n<6;n++){
                int s = sbase + n;
                float cc = fsig(acc[n][1])*c0r[n] + fsig(acc[n][0])*ftanh(acc[n][2]);
                float hh = fsig(acc[n][3])*ftanh(cc);
                c0r[n] = cc;
                sm[IN0 + s*196 + 65 + j] = hh;
                sm[IN1 + s*260 + j]      = hh;
            }
            __syncthreads();
        }

        // ---------- layer 1 : gates over [h0 | h1], K=256 (65 float4) ----------
        {
            float acc[6][4];
            #pragma unroll
            for (int n=0;n<6;n++){
                #pragma unroll
                for (int g=0;g<4;g++) acc[n][g] = bias1[g];
            }
            float4 wA0 = w1p[j], wA1 = w1p[128+j], wA2 = w1p[256+j], wA3 = w1p[384+j];
            for (int k4=0;k4<65;k4++){
                float4 wB0=wA0, wB1=wA1, wB2=wA2, wB3=wA3;
                if (k4 < 64){
                    const float4* nxt = w1p + (size_t)(k4+1)*512 + j;
                    wB0 = nxt[0]; wB1 = nxt[128]; wB2 = nxt[256]; wB3 = nxt[384];
                }
                #pragma unroll
                for (int n=0;n<6;n++){
                    float4 xv = in1f[(sbase+n)*65 + k4];
                    acc[n][0] = FMA4(xv, wA0, acc[n][0]);
                    acc[n][1] = FMA4(xv, wA1, acc[n][1]);
                    acc[n][2] = FMA4(xv, wA2, acc[n][2]);
                    acc[n][3] = FMA4(xv, wA3, acc[n][3]);
                }
                wA0=wB0; wA1=wB1; wA2=wB2; wA3=wB3;
            }
            __syncthreads();
            #pragma unroll
            for (int n=0;n<6;n++){
                int s = sbase + n;
                float cc = fsig(acc[n][1])*c1r[n] + fsig(acc[n][0])*ftanh(acc[n][2]);
                float hh = fsig(acc[n][3])*ftanh(cc);
                c1r[n] = cc;
                sm[IN1 + s*260 + 128 + j] = hh;
            }
            __syncthreads();
        }

        // ---------- decoder FC (reads IN1 h1 half; races only with disjoint buffers)
        if (step >= DD && t < 184){
            int s = t >> 3, l8 = t & 7;
            float a = 0.f;
            #pragma unroll
            for (int k=0;k<16;k++){
                int jj = l8*16 + k;
                a = fmaf(sm[FCW+jj], sm[IN1 + s*260 + 128 + jj], a);
            }
            a += __shfl_down(a, 4, 8);
            a += __shfl_down(a, 2, 8);
            a += __shfl_down(a, 1, 8);
            if (l8 == 0){
                int sgl = s0 + s; int bb = sgl & 255; int nn = sgl >> 8;
                float yv = fmaxf(a + sm[INFC+s] + sm[FCW+156], 0.f);
                int yd = step - DD;
                outy[((size_t)bb*DY + yd)*DN + nn] = yv;
            }
        }
    }
}

// ---------------------------------------------------------------------------
extern "C" void kernel_launch(void* const* d_in, const int* in_sizes, int n_in,
                              void* d_out, int out_size, void* d_ws, size_t ws_size,
                              hipStream_t stream)
{
    const float* x         = (const float*)d_in[0];
    const float* adj_real  = (const float*)d_in[1];
    const float* infection = (const float*)d_in[2];
    const int*   day_order = (const int*)  d_in[3];
    const float* gl_w1     = (const float*)d_in[4];
    const float* gl_b1     = (const float*)d_in[5];
    const float* gl_w2     = (const float*)d_in[6];
    const float* gl_b2     = (const float*)d_in[7];
    const float* glp       = (const float*)d_in[8];
    const float* gcn_w     = (const float*)d_in[9];
    const float* vvec      = (const float*)d_in[10];
    const float* wih0      = (const float*)d_in[11];
    const float* whh0      = (const float*)d_in[12];
    const float* b0        = (const float*)d_in[13];
    const float* wih1      = (const float*)d_in[14];
    const float* whh1      = (const float*)d_in[15];
    const float* b1        = (const float*)d_in[16];
    const float* fcw       = (const float*)d_in[17];
    const float* fcb       = (const float*)d_in[18];

    float* ws      = (float*)d_ws;
    float* zin     = ws + ZIN_OFF;
    float* wc0     = ws + WC0_OFF;
    float* wc1     = ws + WC1_OFF;
    float* gwt     = ws + GWT_OFF;
    float* out_adj = (float*)d_out;
    float* out_y   = out_adj + ADJSZ;

    kernPrep<<<dim3(944), dim3(256), 0, stream>>>(wih0, whh0, wih1, whh1, gcn_w,
                                                  wc0, wc1, gwt);
    kernA<<<dim3(DB*DD), dim3(256), 0, stream>>>(x, adj_real, infection, day_order,
                                                 gl_w1, gl_b1, gl_w2, gl_b2, glp,
                                                 vvec, gwt, out_adj, zin);
    kernB<<<dim3(DB), dim3(512), 0, stream>>>(zin, wc0, wc1, b0, b1, infection,
                                              fcw, fcb, out_y);
}

// Round 2
// 966.176 us; speedup vs baseline: 2.2671x; 2.2671x over previous
//
#include <hip/hip_runtime.h>
#include <hip/hip_bf16.h>
#include <stdint.h>

// ---------------------------------------------------------------------------
// B=256 D=28 N=23 F=128 O=64 H=128 Y=7.  NBSEQ=5888 = 184 blocks x 32 seqs.
// kernPrep: pack W (bf16, MFMA-A fragment order, gate-grouped rows) + gwt.
// kernA   : per-(b,d) graph stage -> adj (out0) + zin packed bf16 hi/lo in
//           MFMA-B layout [step][blk184][k8 0..8][hi/lo][seq32][8e].
// kernB   : 2-layer LSTM via mfma_f32_16x16x32_bf16, U split hi+lo, W single
//           bf16 streamed from L2; gates of a channel live in one lane.
// ---------------------------------------------------------------------------

#define DB 256
#define DD 28
#define DN 23
#define DF 128
#define DO 64
#define DH 128
#define DY 7
#define NBSEQ (DN*DB)
#define ADJSZ (DB*DD*DN*DN)
#define GBLK 184

// workspace byte offsets
#define ZB_BYTES  47480832u            // 28*184*576*16
#define WB0_OFF   47480832u            // 7*32*64*8*2  = 229376
#define WB1_OFF   47710208u            // 8*32*64*8*2  = 262144
#define GWT_OFFB  47972352u            // 8192 f32

using v8bf  = __attribute__((ext_vector_type(8))) __bf16;
using f32x4 = __attribute__((ext_vector_type(4))) float;

__device__ __forceinline__ float fsig(float x)  { return 1.f/(1.f+__expf(-x)); }
__device__ __forceinline__ float ftanh(float x) { return 1.f - 2.f/(__expf(2.f*x)+1.f); }

__device__ __forceinline__ unsigned short f2bf(float f){
    unsigned u = __builtin_bit_cast(unsigned, f);
    return (unsigned short)((u + 0x7FFFu + ((u>>16)&1u)) >> 16);
}
__device__ __forceinline__ float bf2f(unsigned short b){
    return __builtin_bit_cast(float, (unsigned)b << 16);
}

#define FMA4(xv, wv, a) fmaf((xv).w,(wv).w, fmaf((xv).z,(wv).z, fmaf((xv).y,(wv).y, fmaf((xv).x,(wv).x,(a)))))
#define MFMA_(acc_, A_, B_) acc_ = __builtin_amdgcn_mfma_f32_16x16x32_bf16(A_, B_, acc_, 0, 0, 0)

// ---------------------------------------------------------------------------
// Prep. Wb[kt][mt][lane][e]: A-frag row rit=lane&15 -> (localj=rit>>2, g=rit&3),
// orig row r = g*128 + mt*4 + localj; k = kt*32 + (lane>>4)*8 + e.
// L0 cols: k<65 -> wih0 ; 72<=k<200 -> whh0[k-72] ; else 0.  (x padded to 72)
// L1 cols: k<128 -> wih1 ; else whh1[k-128].
// ---------------------------------------------------------------------------
__global__ __launch_bounds__(256) void kernPrep(
    const float* __restrict__ wih0, const float* __restrict__ whh0,
    const float* __restrict__ wih1, const float* __restrict__ whh1,
    const float* __restrict__ gcn_w,
    unsigned short* __restrict__ wb0, unsigned short* __restrict__ wb1,
    float* __restrict__ gwt)
{
    int idx = blockIdx.x*256 + threadIdx.x;
    if (idx < 114688){
        int e = idx&7, l = (idx>>3)&63, mt = (idx>>9)&31, kt = idx>>14;
        int rit = l&15, lj = rit>>2, g = rit&3;
        int r = g*128 + mt*4 + lj;
        int k = kt*32 + (l>>4)*8 + e;
        float v = 0.f;
        if (k < 65)                 v = wih0[r*65 + k];
        else if (k >= 72 && k < 200) v = whh0[r*128 + (k-72)];
        wb0[idx] = f2bf(v);
        return;
    }
    idx -= 114688;
    if (idx < 131072){
        int e = idx&7, l = (idx>>3)&63, mt = (idx>>9)&31, kt = idx>>14;
        int rit = l&15, lj = rit>>2, g = rit&3;
        int r = g*128 + mt*4 + lj;
        int k = kt*32 + (l>>4)*8 + e;
        float v = (k < 128) ? wih1[r*128 + k] : whh1[r*128 + (k-128)];
        wb1[idx] = f2bf(v);
        return;
    }
    idx -= 131072;
    if (idx < 8192){
        int o = idx >> 7, f = idx & 127;
        gwt[idx] = gcn_w[f*DO + o];     // gwt[o][f]
    }
}

// ---------------------------------------------------------------------------
// Kernel A: per-(b,d) graph stage.  grid = 7168, block = 256.
// ---------------------------------------------------------------------------
__global__ __launch_bounds__(256) void kernA(
    const float* __restrict__ x, const float* __restrict__ adj_real,
    const float* __restrict__ infection, const int* __restrict__ day_order,
    const float* __restrict__ w1, const float* __restrict__ b1,
    const float* __restrict__ w2, const float* __restrict__ b2,
    const float* __restrict__ glp, const float* __restrict__ vvec,
    const float* __restrict__ gwt,
    float* __restrict__ out_adj, uint4* __restrict__ zb4)
{
    const int bd = blockIdx.x;
    const int b  = bd / DD;
    const int d  = bd - b*DD;
    const int t  = threadIdx.x;

    __shared__ float sm[11776];
    const int XS=0, N1=3036, N2=6072, S12=9108, ADJ=9660, XW=10212,
              DEG=11684, DINV=11707, FACT=11730, INFS=11753;
    const int XWP = N1;   // alias (A7 partials; dead before GC reuse)
    const int GC  = N1;   // alias (A8 gcn output)

    const float* xg = x + (size_t)bd * (DN*DF);
    for (int p = t; p < DN*DF; p += 256) {
        int n = p >> 7, f = p & 127;
        sm[XS + n*132 + f] = xg[p];
    }
    if (t < DN) {
        float vv = vvec[t];
        sm[FACT + t] = __expf(vv*vv*(float)day_order[b]);
        sm[INFS + t] = infection[(size_t)bd*DN + t];
    }
    __syncthreads();

    // A2: n1/n2
    {
        const int mat = t >> 7, fo = t & 127;
        const float* wr = (mat ? w2 : w1) + fo*DF;
        const float bias = (mat ? b2 : b1)[fo];
        float acc[DN];
        #pragma unroll
        for (int n=0;n<DN;n++) acc[n]=0.f;
        float4 w4 = *(const float4*)wr;
        for (int k4=0;k4<32;k4++){
            float4 wn = w4;
            if (k4 < 31) wn = *(const float4*)(wr + 4*(k4+1));
            #pragma unroll
            for (int n=0;n<DN;n++){
                float4 xv = *(const float4*)&sm[XS + n*132 + 4*k4];
                acc[n] = FMA4(xv, w4, acc[n]);
            }
            w4 = wn;
        }
        const int dst = mat ? N2 : N1;
        #pragma unroll
        for (int n=0;n<DN;n++) sm[dst + n*132 + fo] = ftanh(acc[n]+bias);
    }
    __syncthreads();

    // A3: s12 + deg
    if (t < DN) {
        const float* ar = adj_real + (size_t)bd*(DN*DN) + t*DN;
        float s = 0.f;
        for (int m=0;m<DN;m++) s += ar[m];
        sm[DEG+t] = s;
    }
    for (int p=t; p<DN*DN; p+=256){
        int i = p/DN, j = p - i*DN;
        float a = 0.f;
        for (int k4=0;k4<32;k4++){
            float4 av = *(const float4*)&sm[N1 + i*132 + 4*k4];
            float4 bv = *(const float4*)&sm[N2 + j*132 + 4*k4];
            a = FMA4(av, bv, a);
        }
        sm[S12 + i*24 + j] = a;
    }
    __syncthreads();

    // A4: adj
    for (int p=t; p<DN*DN; p+=256){
        int i=p/DN, j=p-i*DN;
        float al  = fmaxf(ftanh(sm[S12+i*24+j]-sm[S12+j*24+i]), 0.f);
        float md  = fsig(glp[i*DN+j]*sm[DEG+i]*sm[DEG+j]);
        float arv = adj_real[(size_t)bd*(DN*DN) + p];
        float adjv = al + md*arv;
        out_adj[(size_t)bd*(DN*DN) + p] = adjv;
        sm[ADJ + i*24 + j] = adjv + (i==j ? 1.f : 0.f);
    }
    __syncthreads();

    if (t<DN){
        float rs=0.f;
        for (int jj=0;jj<DN;jj++) rs += sm[ADJ+t*24+jj];
        sm[DINV+t] = rsqrtf(rs);
    }
    __syncthreads();
    for (int p=t;p<DN*DN;p+=256){
        int i=p/DN, j=p-i*DN;
        sm[ADJ+i*24+j] *= sm[DINV+i]*sm[DINV+j];
    }
    __syncthreads();

    // A7: xw = x @ gcn_w (k split 4 ways)
    {
        const int o = t & 63, q = t >> 6;
        float acc[DN];
        #pragma unroll
        for (int n=0;n<DN;n++) acc[n]=0.f;
        const float* gw = gwt + o*DF + q*32;
        for (int k4=0;k4<8;k4++){
            float4 w4 = *(const float4*)(gw + 4*k4);
            #pragma unroll
            for (int n=0;n<DN;n++){
                float4 xv = *(const float4*)&sm[XS + n*132 + q*32 + 4*k4];
                acc[n] = FMA4(xv, w4, acc[n]);
            }
        }
        #pragma unroll
        for (int n=0;n<DN;n++) sm[XWP + (q*DN+n)*64 + o] = acc[n];
    }
    __syncthreads();
    for (int p=t;p<DN*64;p+=256){
        int n=p>>6, o=p&63;
        sm[XW+p] = sm[XWP + n*64 + o] + sm[XWP + (DN+n)*64 + o]
                 + sm[XWP + (2*DN+n)*64 + o] + sm[XWP + (3*DN+n)*64 + o];
    }
    __syncthreads();

    // A8: gcn -> GC (factor applied)
    for (int p=t;p<DN*64;p+=256){
        int n=p>>6, o=p&63;
        float a=0.f;
        #pragma unroll
        for (int m=0;m<DN;m++) a = fmaf(sm[ADJ+n*24+m], sm[XW+m*64+o], a);
        sm[GC + p] = fmaxf(a,0.f)*sm[FACT+n];
    }
    __syncthreads();

    // pack: per (n, k8 0..8, hi/lo): 8 elems -> one uint4
    for (int p=t; p<DN*18; p+=256){
        int n = p/18, r = p - n*18, k8 = r>>1, hsel = r&1;
        __align__(16) unsigned short ob[8];
        #pragma unroll
        for (int e=0;e<8;e++){
            int k = k8*8+e;
            float v = (k<64) ? sm[GC + n*64 + k] : ((k==64) ? sm[INFS+n] : 0.f);
            unsigned short hb = f2bf(v);
            ob[e] = hsel ? f2bf(v - bf2f(hb)) : hb;
        }
        int gseq = n*DB + b;
        int blkz = gseq >> 5, seq = gseq & 31;
        zb4[(size_t)(d*GBLK + blkz)*576 + hsel*288 + k8*32 + seq] = *(const uint4*)ob;
    }
}

// ---------------------------------------------------------------------------
// Kernel B: MFMA LSTM.  grid=184, block=512 (8 waves).  Wave w: M-tiles 4w..4w+3.
// Lane: lhi=l>>4 -> local channel, llo=l&15 -> seq within N-tile.
// acc[mi][nt] f32x4: regs = gates (i,f,g,o) of channel j=16w+mi*4+lhi, seq=nt*16+llo.
// ---------------------------------------------------------------------------
#define U0HI 0
#define U0LO 14336
#define U1HI 28672
#define U1LO 45056
#define FCWO 61440
#define INFCO 61956

__global__ __launch_bounds__(512) void kernB(
    const uint4* __restrict__ zb4, const v8bf* __restrict__ w0p, const v8bf* __restrict__ w1p,
    const float* __restrict__ b0g, const float* __restrict__ b1g,
    const float* __restrict__ infection, const float* __restrict__ fcw,
    const float* __restrict__ fcb, float* __restrict__ outy)
{
    const int t = threadIdx.x, blk = blockIdx.x;
    const int w = t>>6, l = t&63;
    const int lhi = l>>4, llo = l&15;
    __shared__ __align__(16) unsigned char smraw[62084];
    char* smb = (char*)smraw;

    // zero U0/U1 (61440 B)
    for (int i = t; i < 61440/16; i += 512){
        uint4 z; z.x=z.y=z.z=z.w=0u;
        ((uint4*)smraw)[i] = z;
    }
    if (t < 129) ((float*)(smb+FCWO))[t] = (t<128) ? fcw[t] : fcb[0];
    if (t < 32){
        int gseq = blk*32 + t, n = gseq>>8, bb = gseq&255;
        float a = 0.f;
        for (int dd=0; dd<DD; dd++)
            a = fmaf(fcw[128+dd], infection[((size_t)bb*DD+dd)*DN+n], a);
        ((float*)(smb+INFCO))[t] = a;
    }
    float bs0[4][4], bs1[4][4];
    #pragma unroll
    for (int mi=0;mi<4;mi++){
        int j = 16*w + mi*4 + lhi;
        #pragma unroll
        for (int g=0; g<4; g++){ bs0[mi][g] = b0g[g*128+j]; bs1[mi][g] = b1g[g*128+j]; }
    }
    float c0[4][2] = {}, c1[4][2] = {};
    float x2r[8];
    #pragma unroll
    for (int e=0;e<8;e++) x2r[e] = 0.f;
    __syncthreads();

    // stage step 0 (x part of U0): unit u = w*72 + i, hi units 0..287, lo 288..575
    {
        const uint4* src = zb4 + (size_t)blk*576;
        int u = w*72 + l;
        uint4 a0 = src[u];
        int d0 = (u<288) ? u*16 : (U0LO + (u-288)*16);
        *(uint4*)(smb + d0) = a0;
        if (l < 8){
            int u2 = u + 64;
            uint4 a1 = src[u2];
            int d1 = (u2<288) ? u2*16 : (U0LO + (u2-288)*16);
            *(uint4*)(smb + d1) = a1;
        }
    }
    __syncthreads();

    for (int step = 0; step < DD + DY; ++step){
        // ---- running input mean (encoder) / build decoder input (step 28)
        if (step < DD){
            if (t < 288){
                uint4 hv = *(const uint4*)(smb + U0HI + t*16);
                uint4 lv = *(const uint4*)(smb + U0LO + t*16);
                const unsigned short* hp = (const unsigned short*)&hv;
                const unsigned short* lp = (const unsigned short*)&lv;
                #pragma unroll
                for (int e=0;e<8;e++) x2r[e] += bf2f(hp[e]) + bf2f(lp[e]);
            }
        } else if (step == DD){
            if (t < 288){
                __align__(16) unsigned short hb8[8], lb8[8];
                #pragma unroll
                for (int e=0;e<8;e++){
                    float v = x2r[e] * (1.f/(float)DD);
                    unsigned short h = f2bf(v);
                    hb8[e] = h;
                    lb8[e] = f2bf(v - bf2f(h));
                }
                *(uint4*)(smb + U0HI + t*16) = *(const uint4*)hb8;
                *(uint4*)(smb + U0LO + t*16) = *(const uint4*)lb8;
            }
            __syncthreads();
        }

        // ---------------- layer 0: G = W0 @ [x|h0], 7 k-tiles ----------------
        {
            f32x4 acc[4][2];
            #pragma unroll
            for (int mi=0;mi<4;mi++){
                #pragma unroll
                for (int nt=0;nt<2;nt++){
                    f32x4 a; a[0]=bs0[mi][0]; a[1]=bs0[mi][1]; a[2]=bs0[mi][2]; a[3]=bs0[mi][3];
                    acc[mi][nt] = a;
                }
            }
            #pragma unroll
            for (int kt=0; kt<7; ++kt){
                const v8bf* wrow = w0p + (size_t)(kt*32 + w*4)*64 + l;
                v8bf A0 = wrow[0], A1 = wrow[64], A2 = wrow[128], A3 = wrow[192];
                int bu = (kt*4 + lhi)*32 + llo;
                v8bf BH0 = *(const v8bf*)(smb + U0HI + bu*16);
                v8bf BH1 = *(const v8bf*)(smb + U0HI + (bu+16)*16);
                v8bf BL0 = *(const v8bf*)(smb + U0LO + bu*16);
                v8bf BL1 = *(const v8bf*)(smb + U0LO + (bu+16)*16);
                MFMA_(acc[0][0], A0, BH0); MFMA_(acc[0][0], A0, BL0);
                MFMA_(acc[1][0], A1, BH0); MFMA_(acc[1][0], A1, BL0);
                MFMA_(acc[2][0], A2, BH0); MFMA_(acc[2][0], A2, BL0);
                MFMA_(acc[3][0], A3, BH0); MFMA_(acc[3][0], A3, BL0);
                MFMA_(acc[0][1], A0, BH1); MFMA_(acc[0][1], A0, BL1);
                MFMA_(acc[1][1], A1, BH1); MFMA_(acc[1][1], A1, BL1);
                MFMA_(acc[2][1], A2, BH1); MFMA_(acc[2][1], A2, BL1);
                MFMA_(acc[3][1], A3, BH1); MFMA_(acc[3][1], A3, BL1);
            }
            __syncthreads();   // B2: all U0 reads done

            // issue next-step x loads (written to LDS after L1)
            uint4 sv0, sv1; sv0.x=sv0.y=sv0.z=sv0.w=0u; sv1 = sv0;
            const bool do_stage = (step + 1 < DD);
            if (do_stage){
                const uint4* src = zb4 + (size_t)((step+1)*GBLK + blk)*576;
                sv0 = src[w*72 + l];
                if (l < 8) sv1 = src[w*72 + 64 + l];
            }

            // activation L0 + h0 writes (U0 h-region + U1 h0-region)
            #pragma unroll
            for (int mi=0;mi<4;mi++){
                int j = 16*w + mi*4 + lhi;
                int j8 = j>>3, je = j&7;
                #pragma unroll
                for (int nt=0;nt<2;nt++){
                    f32x4 a = acc[mi][nt];
                    float ii = fsig(a[0]), ff = fsig(a[1]), gg = ftanh(a[2]), oo = fsig(a[3]);
                    float c = ff*c0[mi][nt] + ii*gg;  c0[mi][nt] = c;
                    float h = oo*ftanh(c);
                    unsigned short hb = f2bf(h);
                    unsigned short lb = f2bf(h - bf2f(hb));
                    int seq = nt*16 + llo;
                    ((unsigned short*)(smb+U0HI))[((9+j8)*32+seq)*8 + je] = hb;
                    ((unsigned short*)(smb+U0LO))[((9+j8)*32+seq)*8 + je] = lb;
                    ((unsigned short*)(smb+U1HI))[(j8*32+seq)*8 + je]     = hb;
                    ((unsigned short*)(smb+U1LO))[(j8*32+seq)*8 + je]     = lb;
                }
            }
            __syncthreads();   // B3: h0 visible

            // ---------------- layer 1: G = W1 @ [h0|h1], 8 k-tiles ----------------
            f32x4 acc1[4][2];
            #pragma unroll
            for (int mi=0;mi<4;mi++){
                #pragma unroll
                for (int nt=0;nt<2;nt++){
                    f32x4 a; a[0]=bs1[mi][0]; a[1]=bs1[mi][1]; a[2]=bs1[mi][2]; a[3]=bs1[mi][3];
                    acc1[mi][nt] = a;
                }
            }
            #pragma unroll
            for (int kt=0; kt<8; ++kt){
                const v8bf* wrow = w1p + (size_t)(kt*32 + w*4)*64 + l;
                v8bf A0 = wrow[0], A1 = wrow[64], A2 = wrow[128], A3 = wrow[192];
                int bu = (kt*4 + lhi)*32 + llo;
                v8bf BH0 = *(const v8bf*)(smb + U1HI + bu*16);
                v8bf BH1 = *(const v8bf*)(smb + U1HI + (bu+16)*16);
                v8bf BL0 = *(const v8bf*)(smb + U1LO + bu*16);
                v8bf BL1 = *(const v8bf*)(smb + U1LO + (bu+16)*16);
                MFMA_(acc1[0][0], A0, BH0); MFMA_(acc1[0][0], A0, BL0);
                MFMA_(acc1[1][0], A1, BH0); MFMA_(acc1[1][0], A1, BL0);
                MFMA_(acc1[2][0], A2, BH0); MFMA_(acc1[2][0], A2, BL0);
                MFMA_(acc1[3][0], A3, BH0); MFMA_(acc1[3][0], A3, BL0);
                MFMA_(acc1[0][1], A0, BH1); MFMA_(acc1[0][1], A0, BL1);
                MFMA_(acc1[1][1], A1, BH1); MFMA_(acc1[1][1], A1, BL1);
                MFMA_(acc1[2][1], A2, BH1); MFMA_(acc1[2][1], A2, BL1);
                MFMA_(acc1[3][1], A3, BH1); MFMA_(acc1[3][1], A3, BL1);
            }
            __syncthreads();   // B4: all U1 reads done

            if (do_stage){
                int u = w*72 + l;
                int d0 = (u<288) ? u*16 : (U0LO + (u-288)*16);
                *(uint4*)(smb + d0) = sv0;
                if (l < 8){
                    int u2 = u + 64;
                    int d1 = (u2<288) ? u2*16 : (U0LO + (u2-288)*16);
                    *(uint4*)(smb + d1) = sv1;
                }
            }

            // activation L1 + h1 writes
            #pragma unroll
            for (int mi=0;mi<4;mi++){
                int j = 16*w + mi*4 + lhi;
                int j8 = j>>3, je = j&7;
                #pragma unroll
                for (int nt=0;nt<2;nt++){
                    f32x4 a = acc1[mi][nt];
                    float ii = fsig(a[0]), ff = fsig(a[1]), gg = ftanh(a[2]), oo = fsig(a[3]);
                    float c = ff*c1[mi][nt] + ii*gg;  c1[mi][nt] = c;
                    float h = oo*ftanh(c);
                    unsigned short hb = f2bf(h);
                    unsigned short lb = f2bf(h - bf2f(hb));
                    int seq = nt*16 + llo;
                    ((unsigned short*)(smb+U1HI))[((16+j8)*32+seq)*8 + je] = hb;
                    ((unsigned short*)(smb+U1LO))[((16+j8)*32+seq)*8 + je] = lb;
                }
            }
        }

        // ---- decoder FC
        if (step >= DD){
            __syncthreads();   // h1 visible
            if (t < 256){
                int seq = t>>3, l8 = t&7;
                const unsigned short* uh = (const unsigned short*)(smb+U1HI);
                const unsigned short* ul = (const unsigned short*)(smb+U1LO);
                const float* fw = (const float*)(smb+FCWO);
                float a = 0.f;
                #pragma unroll
                for (int half=0; half<2; ++half){
                    int k8 = 16 + l8*2 + half;
                    int base = (k8*32 + seq)*8;
                    #pragma unroll
                    for (int e=0;e<8;e++){
                        int j = l8*16 + half*8 + e;
                        a = fmaf(fw[j], bf2f(uh[base+e]) + bf2f(ul[base+e]), a);
                    }
                }
                a += __shfl_down(a, 4, 8);
                a += __shfl_down(a, 2, 8);
                a += __shfl_down(a, 1, 8);
                if (l8 == 0){
                    int gseq = blk*32 + seq, n = gseq>>8, bb = gseq&255;
                    float yv = fmaxf(a + ((const float*)(smb+INFCO))[seq] + fw[128], 0.f);
                    outy[((size_t)bb*DY + (step-DD))*DN + n] = yv;
                }
            }
        }
        __syncthreads();   // close step (staging writes / FC reads before next iter)
    }
}

// ---------------------------------------------------------------------------
extern "C" void kernel_launch(void* const* d_in, const int* in_sizes, int n_in,
                              void* d_out, int out_size, void* d_ws, size_t ws_size,
                              hipStream_t stream)
{
    const float* x         = (const float*)d_in[0];
    const float* adj_real  = (const float*)d_in[1];
    const float* infection = (const float*)d_in[2];
    const int*   day_order = (const int*)  d_in[3];
    const float* gl_w1     = (const float*)d_in[4];
    const float* gl_b1     = (const float*)d_in[5];
    const float* gl_w2     = (const float*)d_in[6];
    const float* gl_b2     = (const float*)d_in[7];
    const float* glp       = (const float*)d_in[8];
    const float* gcn_w     = (const float*)d_in[9];
    const float* vvec      = (const float*)d_in[10];
    const float* wih0      = (const float*)d_in[11];
    const float* whh0      = (const float*)d_in[12];
    const float* b0        = (const float*)d_in[13];
    const float* wih1      = (const float*)d_in[14];
    const float* whh1      = (const float*)d_in[15];
    const float* b1        = (const float*)d_in[16];
    const float* fcw       = (const float*)d_in[17];
    const float* fcb       = (const float*)d_in[18];

    uint8_t* wsb = (uint8_t*)d_ws;
    unsigned short* zb  = (unsigned short*)(wsb);
    unsigned short* wb0 = (unsigned short*)(wsb + WB0_OFF);
    unsigned short* wb1 = (unsigned short*)(wsb + WB1_OFF);
    float*          gwt = (float*)(wsb + GWT_OFFB);
    float* out_adj = (float*)d_out;
    float* out_y   = out_adj + ADJSZ;

    kernPrep<<<dim3(992), dim3(256), 0, stream>>>(wih0, whh0, wih1, whh1, gcn_w,
                                                  wb0, wb1, gwt);
    kernA<<<dim3(DB*DD), dim3(256), 0, stream>>>(x, adj_real, infection, day_order,
                                                 gl_w1, gl_b1, gl_w2, gl_b2, glp,
                                                 vvec, gwt, out_adj, (uint4*)zb);
    kernB<<<dim3(GBLK), dim3(512), 0, stream>>>((const uint4*)zb, (const v8bf*)wb0,
                                                (const v8bf*)wb1, b0, b1, infection,
                                                fcw, fcb, out_y);
}

// Round 3
// 959.076 us; speedup vs baseline: 2.2839x; 1.0074x over previous
//
#include <hip/hip_runtime.h>
#include <hip/hip_bf16.h>
#include <stdint.h>

// ---------------------------------------------------------------------------
// B=256 D=28 N=23 F=128 O=64 H=128 Y=7.  NBSEQ=5888 = 184 blocks x 32 seqs.
// kernPrep: pack W (bf16, MFMA-A fragment order, gate-grouped rows) + gwt.
// kernA   : per-(b,d) graph stage -> adj (out0) + zin packed bf16 hi/lo in
//           MFMA-B layout [step][blk184][k8 0..8][hi/lo][seq32][8e].
// kernB   : 2-layer LSTM via mfma_f32_16x16x32_bf16, U split hi+lo, W single
//           bf16 streamed from L2; gates of a channel live in one lane.
// R3: __launch_bounds__(512,2) on kernB (VGPR budget 256; R2 spilled at 128 ->
//     654 MB scratch FETCH).  Non-temporal zin loads + output stores.
// ---------------------------------------------------------------------------

#define DB 256
#define DD 28
#define DN 23
#define DF 128
#define DO 64
#define DH 128
#define DY 7
#define NBSEQ (DN*DB)
#define ADJSZ (DB*DD*DN*DN)
#define GBLK 184

// workspace byte offsets
#define ZB_BYTES  47480832u            // 28*184*576*16
#define WB0_OFF   47480832u            // 7*32*64*8*2  = 229376
#define WB1_OFF   47710208u            // 8*32*64*8*2  = 262144
#define GWT_OFFB  47972352u            // 8192 f32

using v8bf  = __attribute__((ext_vector_type(8))) __bf16;
using f32x4 = __attribute__((ext_vector_type(4))) float;
using u32x4 = __attribute__((ext_vector_type(4))) unsigned int;

__device__ __forceinline__ float fsig(float x)  { return 1.f/(1.f+__expf(-x)); }
__device__ __forceinline__ float ftanh(float x) { return 1.f - 2.f/(__expf(2.f*x)+1.f); }

__device__ __forceinline__ unsigned short f2bf(float f){
    unsigned u = __builtin_bit_cast(unsigned, f);
    return (unsigned short)((u + 0x7FFFu + ((u>>16)&1u)) >> 16);
}
__device__ __forceinline__ float bf2f(unsigned short b){
    return __builtin_bit_cast(float, (unsigned)b << 16);
}
__device__ __forceinline__ uint4 ntload4(const uint4* p){
    u32x4 v = __builtin_nontemporal_load((const u32x4*)p);
    return *(uint4*)&v;
}

#define FMA4(xv, wv, a) fmaf((xv).w,(wv).w, fmaf((xv).z,(wv).z, fmaf((xv).y,(wv).y, fmaf((xv).x,(wv).x,(a)))))
#define MFMA_(acc_, A_, B_) acc_ = __builtin_amdgcn_mfma_f32_16x16x32_bf16(A_, B_, acc_, 0, 0, 0)

// ---------------------------------------------------------------------------
// Prep. Wb[kt][mt][lane][e]: A-frag row rit=lane&15 -> (localj=rit>>2, g=rit&3),
// orig row r = g*128 + mt*4 + localj; k = kt*32 + (lane>>4)*8 + e.
// L0 cols: k<65 -> wih0 ; 72<=k<200 -> whh0[k-72] ; else 0.  (x padded to 72)
// L1 cols: k<128 -> wih1 ; else whh1[k-128].
// ---------------------------------------------------------------------------
__global__ __launch_bounds__(256) void kernPrep(
    const float* __restrict__ wih0, const float* __restrict__ whh0,
    const float* __restrict__ wih1, const float* __restrict__ whh1,
    const float* __restrict__ gcn_w,
    unsigned short* __restrict__ wb0, unsigned short* __restrict__ wb1,
    float* __restrict__ gwt)
{
    int idx = blockIdx.x*256 + threadIdx.x;
    if (idx < 114688){
        int e = idx&7, l = (idx>>3)&63, mt = (idx>>9)&31, kt = idx>>14;
        int rit = l&15, lj = rit>>2, g = rit&3;
        int r = g*128 + mt*4 + lj;
        int k = kt*32 + (l>>4)*8 + e;
        float v = 0.f;
        if (k < 65)                 v = wih0[r*65 + k];
        else if (k >= 72 && k < 200) v = whh0[r*128 + (k-72)];
        wb0[idx] = f2bf(v);
        return;
    }
    idx -= 114688;
    if (idx < 131072){
        int e = idx&7, l = (idx>>3)&63, mt = (idx>>9)&31, kt = idx>>14;
        int rit = l&15, lj = rit>>2, g = rit&3;
        int r = g*128 + mt*4 + lj;
        int k = kt*32 + (l>>4)*8 + e;
        float v = (k < 128) ? wih1[r*128 + k] : whh1[r*128 + (k-128)];
        wb1[idx] = f2bf(v);
        return;
    }
    idx -= 131072;
    if (idx < 8192){
        int o = idx >> 7, f = idx & 127;
        gwt[idx] = gcn_w[f*DO + o];     // gwt[o][f]
    }
}

// ---------------------------------------------------------------------------
// Kernel A: per-(b,d) graph stage.  grid = 7168, block = 256.
// ---------------------------------------------------------------------------
__global__ __launch_bounds__(256) void kernA(
    const float* __restrict__ x, const float* __restrict__ adj_real,
    const float* __restrict__ infection, const int* __restrict__ day_order,
    const float* __restrict__ w1, const float* __restrict__ b1,
    const float* __restrict__ w2, const float* __restrict__ b2,
    const float* __restrict__ glp, const float* __restrict__ vvec,
    const float* __restrict__ gwt,
    float* __restrict__ out_adj, uint4* __restrict__ zb4)
{
    const int bd = blockIdx.x;
    const int b  = bd / DD;
    const int d  = bd - b*DD;
    const int t  = threadIdx.x;

    __shared__ float sm[11776];
    const int XS=0, N1=3036, N2=6072, S12=9108, ADJ=9660, XW=10212,
              DEG=11684, DINV=11707, FACT=11730, INFS=11753;
    const int XWP = N1;   // alias (A7 partials; dead before GC reuse)
    const int GC  = N1;   // alias (A8 gcn output)

    const float* xg = x + (size_t)bd * (DN*DF);
    for (int p = t; p < DN*DF; p += 256) {
        int n = p >> 7, f = p & 127;
        sm[XS + n*132 + f] = xg[p];
    }
    if (t < DN) {
        float vv = vvec[t];
        sm[FACT + t] = __expf(vv*vv*(float)day_order[b]);
        sm[INFS + t] = infection[(size_t)bd*DN + t];
    }
    __syncthreads();

    // A2: n1/n2
    {
        const int mat = t >> 7, fo = t & 127;
        const float* wr = (mat ? w2 : w1) + fo*DF;
        const float bias = (mat ? b2 : b1)[fo];
        float acc[DN];
        #pragma unroll
        for (int n=0;n<DN;n++) acc[n]=0.f;
        float4 w4 = *(const float4*)wr;
        for (int k4=0;k4<32;k4++){
            float4 wn = w4;
            if (k4 < 31) wn = *(const float4*)(wr + 4*(k4+1));
            #pragma unroll
            for (int n=0;n<DN;n++){
                float4 xv = *(const float4*)&sm[XS + n*132 + 4*k4];
                acc[n] = FMA4(xv, w4, acc[n]);
            }
            w4 = wn;
        }
        const int dst = mat ? N2 : N1;
        #pragma unroll
        for (int n=0;n<DN;n++) sm[dst + n*132 + fo] = ftanh(acc[n]+bias);
    }
    __syncthreads();

    // A3: s12 + deg
    if (t < DN) {
        const float* ar = adj_real + (size_t)bd*(DN*DN) + t*DN;
        float s = 0.f;
        for (int m=0;m<DN;m++) s += ar[m];
        sm[DEG+t] = s;
    }
    for (int p=t; p<DN*DN; p+=256){
        int i = p/DN, j = p - i*DN;
        float a = 0.f;
        for (int k4=0;k4<32;k4++){
            float4 av = *(const float4*)&sm[N1 + i*132 + 4*k4];
            float4 bv = *(const float4*)&sm[N2 + j*132 + 4*k4];
            a = FMA4(av, bv, a);
        }
        sm[S12 + i*24 + j] = a;
    }
    __syncthreads();

    // A4: adj
    for (int p=t; p<DN*DN; p+=256){
        int i=p/DN, j=p-i*DN;
        float al  = fmaxf(ftanh(sm[S12+i*24+j]-sm[S12+j*24+i]), 0.f);
        float md  = fsig(glp[i*DN+j]*sm[DEG+i]*sm[DEG+j]);
        float arv = adj_real[(size_t)bd*(DN*DN) + p];
        float adjv = al + md*arv;
        __builtin_nontemporal_store(adjv, &out_adj[(size_t)bd*(DN*DN) + p]);
        sm[ADJ + i*24 + j] = adjv + (i==j ? 1.f : 0.f);
    }
    __syncthreads();

    if (t<DN){
        float rs=0.f;
        for (int jj=0;jj<DN;jj++) rs += sm[ADJ+t*24+jj];
        sm[DINV+t] = rsqrtf(rs);
    }
    __syncthreads();
    for (int p=t;p<DN*DN;p+=256){
        int i=p/DN, j=p-i*DN;
        sm[ADJ+i*24+j] *= sm[DINV+i]*sm[DINV+j];
    }
    __syncthreads();

    // A7: xw = x @ gcn_w (k split 4 ways)
    {
        const int o = t & 63, q = t >> 6;
        float acc[DN];
        #pragma unroll
        for (int n=0;n<DN;n++) acc[n]=0.f;
        const float* gw = gwt + o*DF + q*32;
        for (int k4=0;k4<8;k4++){
            float4 w4 = *(const float4*)(gw + 4*k4);
            #pragma unroll
            for (int n=0;n<DN;n++){
                float4 xv = *(const float4*)&sm[XS + n*132 + q*32 + 4*k4];
                acc[n] = FMA4(xv, w4, acc[n]);
            }
        }
        #pragma unroll
        for (int n=0;n<DN;n++) sm[XWP + (q*DN+n)*64 + o] = acc[n];
    }
    __syncthreads();
    for (int p=t;p<DN*64;p+=256){
        int n=p>>6, o=p&63;
        sm[XW+p] = sm[XWP + n*64 + o] + sm[XWP + (DN+n)*64 + o]
                 + sm[XWP + (2*DN+n)*64 + o] + sm[XWP + (3*DN+n)*64 + o];
    }
    __syncthreads();

    // A8: gcn -> GC (factor applied)
    for (int p=t;p<DN*64;p+=256){
        int n=p>>6, o=p&63;
        float a=0.f;
        #pragma unroll
        for (int m=0;m<DN;m++) a = fmaf(sm[ADJ+n*24+m], sm[XW+m*64+o], a);
        sm[GC + p] = fmaxf(a,0.f)*sm[FACT+n];
    }
    __syncthreads();

    // pack: per (n, k8 0..8, hi/lo): 8 elems -> one uint4
    for (int p=t; p<DN*18; p+=256){
        int n = p/18, r = p - n*18, k8 = r>>1, hsel = r&1;
        __align__(16) unsigned short ob[8];
        #pragma unroll
        for (int e=0;e<8;e++){
            int k = k8*8+e;
            float v = (k<64) ? sm[GC + n*64 + k] : ((k==64) ? sm[INFS+n] : 0.f);
            unsigned short hb = f2bf(v);
            ob[e] = hsel ? f2bf(v - bf2f(hb)) : hb;
        }
        int gseq = n*DB + b;
        int blkz = gseq >> 5, seq = gseq & 31;
        zb4[(size_t)(d*GBLK + blkz)*576 + hsel*288 + k8*32 + seq] = *(const uint4*)ob;
    }
}

// ---------------------------------------------------------------------------
// Kernel B: MFMA LSTM.  grid=184, block=512 (8 waves).  Wave w: M-tiles 4w..4w+3.
// Lane: lhi=l>>4 -> local channel, llo=l&15 -> seq within N-tile.
// acc[mi][nt] f32x4: regs = gates (i,f,g,o) of channel j=16w+mi*4+lhi, seq=nt*16+llo.
// __launch_bounds__(512,2): 2 waves/EU -> 256-VGPR budget, no spills (R2 fix).
// ---------------------------------------------------------------------------
#define U0HI 0
#define U0LO 14336
#define U1HI 28672
#define U1LO 45056
#define FCWO 61440
#define INFCO 61956

__global__ __launch_bounds__(512, 2) void kernB(
    const uint4* __restrict__ zb4, const v8bf* __restrict__ w0p, const v8bf* __restrict__ w1p,
    const float* __restrict__ b0g, const float* __restrict__ b1g,
    const float* __restrict__ infection, const float* __restrict__ fcw,
    const float* __restrict__ fcb, float* __restrict__ outy)
{
    const int t = threadIdx.x, blk = blockIdx.x;
    const int w = t>>6, l = t&63;
    const int lhi = l>>4, llo = l&15;
    __shared__ __align__(16) unsigned char smraw[62084];
    char* smb = (char*)smraw;

    // zero U0/U1 (61440 B)
    for (int i = t; i < 61440/16; i += 512){
        uint4 z; z.x=z.y=z.z=z.w=0u;
        ((uint4*)smraw)[i] = z;
    }
    if (t < 129) ((float*)(smb+FCWO))[t] = (t<128) ? fcw[t] : fcb[0];
    if (t < 32){
        int gseq = blk*32 + t, n = gseq>>8, bb = gseq&255;
        float a = 0.f;
        for (int dd=0; dd<DD; dd++)
            a = fmaf(fcw[128+dd], infection[((size_t)bb*DD+dd)*DN+n], a);
        ((float*)(smb+INFCO))[t] = a;
    }
    float bs0[4][4], bs1[4][4];
    #pragma unroll
    for (int mi=0;mi<4;mi++){
        int j = 16*w + mi*4 + lhi;
        #pragma unroll
        for (int g=0; g<4; g++){ bs0[mi][g] = b0g[g*128+j]; bs1[mi][g] = b1g[g*128+j]; }
    }
    float c0[4][2] = {}, c1[4][2] = {};
    float x2r[8];
    #pragma unroll
    for (int e=0;e<8;e++) x2r[e] = 0.f;
    __syncthreads();

    // stage step 0 (x part of U0): unit u = w*72 + i, hi units 0..287, lo 288..575
    {
        const uint4* src = zb4 + (size_t)blk*576;
        int u = w*72 + l;
        uint4 a0 = ntload4(src + u);
        int d0 = (u<288) ? u*16 : (U0LO + (u-288)*16);
        *(uint4*)(smb + d0) = a0;
        if (l < 8){
            int u2 = u + 64;
            uint4 a1 = ntload4(src + u2);
            int d1 = (u2<288) ? u2*16 : (U0LO + (u2-288)*16);
            *(uint4*)(smb + d1) = a1;
        }
    }
    __syncthreads();

    for (int step = 0; step < DD + DY; ++step){
        // ---- running input mean (encoder) / build decoder input (step 28)
        if (step < DD){
            if (t < 288){
                uint4 hv = *(const uint4*)(smb + U0HI + t*16);
                uint4 lv = *(const uint4*)(smb + U0LO + t*16);
                const unsigned short* hp = (const unsigned short*)&hv;
                const unsigned short* lp = (const unsigned short*)&lv;
                #pragma unroll
                for (int e=0;e<8;e++) x2r[e] += bf2f(hp[e]) + bf2f(lp[e]);
            }
        } else if (step == DD){
            if (t < 288){
                __align__(16) unsigned short hb8[8], lb8[8];
                #pragma unroll
                for (int e=0;e<8;e++){
                    float v = x2r[e] * (1.f/(float)DD);
                    unsigned short h = f2bf(v);
                    hb8[e] = h;
                    lb8[e] = f2bf(v - bf2f(h));
                }
                *(uint4*)(smb + U0HI + t*16) = *(const uint4*)hb8;
                *(uint4*)(smb + U0LO + t*16) = *(const uint4*)lb8;
            }
            __syncthreads();
        }

        // ---------------- layer 0: G = W0 @ [x|h0], 7 k-tiles ----------------
        {
            f32x4 acc[4][2];
            #pragma unroll
            for (int mi=0;mi<4;mi++){
                #pragma unroll
                for (int nt=0;nt<2;nt++){
                    f32x4 a; a[0]=bs0[mi][0]; a[1]=bs0[mi][1]; a[2]=bs0[mi][2]; a[3]=bs0[mi][3];
                    acc[mi][nt] = a;
                }
            }
            #pragma unroll
            for (int kt=0; kt<7; ++kt){
                const v8bf* wrow = w0p + (size_t)(kt*32 + w*4)*64 + l;
                v8bf A0 = wrow[0], A1 = wrow[64], A2 = wrow[128], A3 = wrow[192];
                int bu = (kt*4 + lhi)*32 + llo;
                v8bf BH0 = *(const v8bf*)(smb + U0HI + bu*16);
                v8bf BH1 = *(const v8bf*)(smb + U0HI + (bu+16)*16);
                v8bf BL0 = *(const v8bf*)(smb + U0LO + bu*16);
                v8bf BL1 = *(const v8bf*)(smb + U0LO + (bu+16)*16);
                MFMA_(acc[0][0], A0, BH0); MFMA_(acc[0][0], A0, BL0);
                MFMA_(acc[1][0], A1, BH0); MFMA_(acc[1][0], A1, BL0);
                MFMA_(acc[2][0], A2, BH0); MFMA_(acc[2][0], A2, BL0);
                MFMA_(acc[3][0], A3, BH0); MFMA_(acc[3][0], A3, BL0);
                MFMA_(acc[0][1], A0, BH1); MFMA_(acc[0][1], A0, BL1);
                MFMA_(acc[1][1], A1, BH1); MFMA_(acc[1][1], A1, BL1);
                MFMA_(acc[2][1], A2, BH1); MFMA_(acc[2][1], A2, BL1);
                MFMA_(acc[3][1], A3, BH1); MFMA_(acc[3][1], A3, BL1);
            }
            __syncthreads();   // B2: all U0 reads done

            // issue next-step x loads (written to LDS after L1)
            uint4 sv0, sv1; sv0.x=sv0.y=sv0.z=sv0.w=0u; sv1 = sv0;
            const bool do_stage = (step + 1 < DD);
            if (do_stage){
                const uint4* src = zb4 + (size_t)((step+1)*GBLK + blk)*576;
                sv0 = ntload4(src + w*72 + l);
                if (l < 8) sv1 = ntload4(src + w*72 + 64 + l);
            }

            // activation L0 + h0 writes (U0 h-region + U1 h0-region)
            #pragma unroll
            for (int mi=0;mi<4;mi++){
                int j = 16*w + mi*4 + lhi;
                int j8 = j>>3, je = j&7;
                #pragma unroll
                for (int nt=0;nt<2;nt++){
                    f32x4 a = acc[mi][nt];
                    float ii = fsig(a[0]), ff = fsig(a[1]), gg = ftanh(a[2]), oo = fsig(a[3]);
                    float c = ff*c0[mi][nt] + ii*gg;  c0[mi][nt] = c;
                    float h = oo*ftanh(c);
                    unsigned short hb = f2bf(h);
                    unsigned short lb = f2bf(h - bf2f(hb));
                    int seq = nt*16 + llo;
                    ((unsigned short*)(smb+U0HI))[((9+j8)*32+seq)*8 + je] = hb;
                    ((unsigned short*)(smb+U0LO))[((9+j8)*32+seq)*8 + je] = lb;
                    ((unsigned short*)(smb+U1HI))[(j8*32+seq)*8 + je]     = hb;
                    ((unsigned short*)(smb+U1LO))[(j8*32+seq)*8 + je]     = lb;
                }
            }
            __syncthreads();   // B3: h0 visible

            // ---------------- layer 1: G = W1 @ [h0|h1], 8 k-tiles ----------------
            f32x4 acc1[4][2];
            #pragma unroll
            for (int mi=0;mi<4;mi++){
                #pragma unroll
                for (int nt=0;nt<2;nt++){
                    f32x4 a; a[0]=bs1[mi][0]; a[1]=bs1[mi][1]; a[2]=bs1[mi][2]; a[3]=bs1[mi][3];
                    acc1[mi][nt] = a;
                }
            }
            #pragma unroll
            for (int kt=0; kt<8; ++kt){
                const v8bf* wrow = w1p + (size_t)(kt*32 + w*4)*64 + l;
                v8bf A0 = wrow[0], A1 = wrow[64], A2 = wrow[128], A3 = wrow[192];
                int bu = (kt*4 + lhi)*32 + llo;
                v8bf BH0 = *(const v8bf*)(smb + U1HI + bu*16);
                v8bf BH1 = *(const v8bf*)(smb + U1HI + (bu+16)*16);
                v8bf BL0 = *(const v8bf*)(smb + U1LO + bu*16);
                v8bf BL1 = *(const v8bf*)(smb + U1LO + (bu+16)*16);
                MFMA_(acc1[0][0], A0, BH0); MFMA_(acc1[0][0], A0, BL0);
                MFMA_(acc1[1][0], A1, BH0); MFMA_(acc1[1][0], A1, BL0);
                MFMA_(acc1[2][0], A2, BH0); MFMA_(acc1[2][0], A2, BL0);
                MFMA_(acc1[3][0], A3, BH0); MFMA_(acc1[3][0], A3, BL0);
                MFMA_(acc1[0][1], A0, BH1); MFMA_(acc1[0][1], A0, BL1);
                MFMA_(acc1[1][1], A1, BH1); MFMA_(acc1[1][1], A1, BL1);
                MFMA_(acc1[2][1], A2, BH1); MFMA_(acc1[2][1], A2, BL1);
                MFMA_(acc1[3][1], A3, BH1); MFMA_(acc1[3][1], A3, BL1);
            }
            __syncthreads();   // B4: all U1 reads done

            if (do_stage){
                int u = w*72 + l;
                int d0 = (u<288) ? u*16 : (U0LO + (u-288)*16);
                *(uint4*)(smb + d0) = sv0;
                if (l < 8){
                    int u2 = u + 64;
                    int d1 = (u2<288) ? u2*16 : (U0LO + (u2-288)*16);
                    *(uint4*)(smb + d1) = sv1;
                }
            }

            // activation L1 + h1 writes
            #pragma unroll
            for (int mi=0;mi<4;mi++){
                int j = 16*w + mi*4 + lhi;
                int j8 = j>>3, je = j&7;
                #pragma unroll
                for (int nt=0;nt<2;nt++){
                    f32x4 a = acc1[mi][nt];
                    float ii = fsig(a[0]), ff = fsig(a[1]), gg = ftanh(a[2]), oo = fsig(a[3]);
                    float c = ff*c1[mi][nt] + ii*gg;  c1[mi][nt] = c;
                    float h = oo*ftanh(c);
                    unsigned short hb = f2bf(h);
                    unsigned short lb = f2bf(h - bf2f(hb));
                    int seq = nt*16 + llo;
                    ((unsigned short*)(smb+U1HI))[((16+j8)*32+seq)*8 + je] = hb;
                    ((unsigned short*)(smb+U1LO))[((16+j8)*32+seq)*8 + je] = lb;
                }
            }
        }

        // ---- decoder FC
        if (step >= DD){
            __syncthreads();   // h1 visible
            if (t < 256){
                int seq = t>>3, l8 = t&7;
                const unsigned short* uh = (const unsigned short*)(smb+U1HI);
                const unsigned short* ul = (const unsigned short*)(smb+U1LO);
                const float* fw = (const float*)(smb+FCWO);
                float a = 0.f;
                #pragma unroll
                for (int half=0; half<2; ++half){
                    int k8 = 16 + l8*2 + half;
                    int base = (k8*32 + seq)*8;
                    #pragma unroll
                    for (int e=0;e<8;e++){
                        int j = l8*16 + half*8 + e;
                        a = fmaf(fw[j], bf2f(uh[base+e]) + bf2f(ul[base+e]), a);
                    }
                }
                a += __shfl_down(a, 4, 8);
                a += __shfl_down(a, 2, 8);
                a += __shfl_down(a, 1, 8);
                if (l8 == 0){
                    int gseq = blk*32 + seq, n = gseq>>8, bb = gseq&255;
                    float yv = fmaxf(a + ((const float*)(smb+INFCO))[seq] + fw[128], 0.f);
                    __builtin_nontemporal_store(yv, &outy[((size_t)bb*DY + (step-DD))*DN + n]);
                }
            }
        }
        __syncthreads();   // close step (staging writes / FC reads before next iter)
    }
}

// ---------------------------------------------------------------------------
extern "C" void kernel_launch(void* const* d_in, const int* in_sizes, int n_in,
                              void* d_out, int out_size, void* d_ws, size_t ws_size,
                              hipStream_t stream)
{
    const float* x         = (const float*)d_in[0];
    const float* adj_real  = (const float*)d_in[1];
    const float* infection = (const float*)d_in[2];
    const int*   day_order = (const int*)  d_in[3];
    const float* gl_w1     = (const float*)d_in[4];
    const float* gl_b1     = (const float*)d_in[5];
    const float* gl_w2     = (const float*)d_in[6];
    const float* gl_b2     = (const float*)d_in[7];
    const float* glp       = (const float*)d_in[8];
    const float* gcn_w     = (const float*)d_in[9];
    const float* vvec      = (const float*)d_in[10];
    const float* wih0      = (const float*)d_in[11];
    const float* whh0      = (const float*)d_in[12];
    const float* b0        = (const float*)d_in[13];
    const float* wih1      = (const float*)d_in[14];
    const float* whh1      = (const float*)d_in[15];
    const float* b1        = (const float*)d_in[16];
    const float* fcw       = (const float*)d_in[17];
    const float* fcb       = (const float*)d_in[18];

    uint8_t* wsb = (uint8_t*)d_ws;
    unsigned short* zb  = (unsigned short*)(wsb);
    unsigned short* wb0 = (unsigned short*)(wsb + WB0_OFF);
    unsigned short* wb1 = (unsigned short*)(wsb + WB1_OFF);
    float*          gwt = (float*)(wsb + GWT_OFFB);
    float* out_adj = (float*)d_out;
    float* out_y   = out_adj + ADJSZ;

    kernPrep<<<dim3(992), dim3(256), 0, stream>>>(wih0, whh0, wih1, whh1, gcn_w,
                                                  wb0, wb1, gwt);
    kernA<<<dim3(DB*DD), dim3(256), 0, stream>>>(x, adj_real, infection, day_order,
                                                 gl_w1, gl_b1, gl_w2, gl_b2, glp,
                                                 vvec, gwt, out_adj, (uint4*)zb);
    kernB<<<dim3(GBLK), dim3(512), 0, stream>>>((const uint4*)zb, (const v8bf*)wb0,
                                                (const v8bf*)wb1, b0, b1, infection,
                                                fcw, fcb, out_y);
}

// Round 4
// 909.725 us; speedup vs baseline: 2.4077x; 1.0542x over previous
//
#include <hip/hip_runtime.h>
#include <hip/hip_bf16.h>
#include <stdint.h>

// ---------------------------------------------------------------------------
// B=256 D=28 N=23 F=128 O=64 H=128 Y=7.  NBSEQ=5888 = 184 blocks x 32 seqs.
// kernPrep: pack W (bf16, MFMA-A fragment order, gate-grouped rows) + gwt.
// kernA   : per-(b,d) graph stage -> adj (out0) + zin packed bf16 hi/lo in
//           MFMA-B layout [step][blk184][k8 0..8][hi/lo][seq32][8e].
// kernB   : 2-layer LSTM via mfma_f32_16x16x32_bf16, U split hi+lo, W single
//           bf16 streamed from L2; gates of a channel live in one lane.
// R4: kill register spills (R2/R3: WRITE 92MB + FETCH 550MB scratch traffic
//     at VGPR=128): biases moved to LDS (-32 VGPR), launch_bounds(512,1)
//     (min 1 wave/EU -> full VGPR budget).
// ---------------------------------------------------------------------------

#define DB 256
#define DD 28
#define DN 23
#define DF 128
#define DO 64
#define DH 128
#define DY 7
#define NBSEQ (DN*DB)
#define ADJSZ (DB*DD*DN*DN)
#define GBLK 184

// workspace byte offsets
#define ZB_BYTES  47480832u            // 28*184*576*16
#define WB0_OFF   47480832u            // 7*32*64*8*2  = 229376
#define WB1_OFF   47710208u            // 8*32*64*8*2  = 262144
#define GWT_OFFB  47972352u            // 8192 f32

using v8bf  = __attribute__((ext_vector_type(8))) __bf16;
using f32x4 = __attribute__((ext_vector_type(4))) float;
using u32x4 = __attribute__((ext_vector_type(4))) unsigned int;

__device__ __forceinline__ float fsig(float x)  { return 1.f/(1.f+__expf(-x)); }
__device__ __forceinline__ float ftanh(float x) { return 1.f - 2.f/(__expf(2.f*x)+1.f); }

__device__ __forceinline__ unsigned short f2bf(float f){
    unsigned u = __builtin_bit_cast(unsigned, f);
    return (unsigned short)((u + 0x7FFFu + ((u>>16)&1u)) >> 16);
}
__device__ __forceinline__ float bf2f(unsigned short b){
    return __builtin_bit_cast(float, (unsigned)b << 16);
}
__device__ __forceinline__ uint4 ntload4(const uint4* p){
    u32x4 v = __builtin_nontemporal_load((const u32x4*)p);
    return *(uint4*)&v;
}

#define FMA4(xv, wv, a) fmaf((xv).w,(wv).w, fmaf((xv).z,(wv).z, fmaf((xv).y,(wv).y, fmaf((xv).x,(wv).x,(a)))))
#define MFMA_(acc_, A_, B_) acc_ = __builtin_amdgcn_mfma_f32_16x16x32_bf16(A_, B_, acc_, 0, 0, 0)

// ---------------------------------------------------------------------------
// Prep. Wb[kt][mt][lane][e]: A-frag row rit=lane&15 -> (localj=rit>>2, g=rit&3),
// orig row r = g*128 + mt*4 + localj; k = kt*32 + (lane>>4)*8 + e.
// L0 cols: k<65 -> wih0 ; 72<=k<200 -> whh0[k-72] ; else 0.  (x padded to 72)
// L1 cols: k<128 -> wih1 ; else whh1[k-128].
// ---------------------------------------------------------------------------
__global__ __launch_bounds__(256) void kernPrep(
    const float* __restrict__ wih0, const float* __restrict__ whh0,
    const float* __restrict__ wih1, const float* __restrict__ whh1,
    const float* __restrict__ gcn_w,
    unsigned short* __restrict__ wb0, unsigned short* __restrict__ wb1,
    float* __restrict__ gwt)
{
    int idx = blockIdx.x*256 + threadIdx.x;
    if (idx < 114688){
        int e = idx&7, l = (idx>>3)&63, mt = (idx>>9)&31, kt = idx>>14;
        int rit = l&15, lj = rit>>2, g = rit&3;
        int r = g*128 + mt*4 + lj;
        int k = kt*32 + (l>>4)*8 + e;
        float v = 0.f;
        if (k < 65)                 v = wih0[r*65 + k];
        else if (k >= 72 && k < 200) v = whh0[r*128 + (k-72)];
        wb0[idx] = f2bf(v);
        return;
    }
    idx -= 114688;
    if (idx < 131072){
        int e = idx&7, l = (idx>>3)&63, mt = (idx>>9)&31, kt = idx>>14;
        int rit = l&15, lj = rit>>2, g = rit&3;
        int r = g*128 + mt*4 + lj;
        int k = kt*32 + (l>>4)*8 + e;
        float v = (k < 128) ? wih1[r*128 + k] : whh1[r*128 + (k-128)];
        wb1[idx] = f2bf(v);
        return;
    }
    idx -= 131072;
    if (idx < 8192){
        int o = idx >> 7, f = idx & 127;
        gwt[idx] = gcn_w[f*DO + o];     // gwt[o][f]
    }
}

// ---------------------------------------------------------------------------
// Kernel A: per-(b,d) graph stage.  grid = 7168, block = 256.
// ---------------------------------------------------------------------------
__global__ __launch_bounds__(256) void kernA(
    const float* __restrict__ x, const float* __restrict__ adj_real,
    const float* __restrict__ infection, const int* __restrict__ day_order,
    const float* __restrict__ w1, const float* __restrict__ b1,
    const float* __restrict__ w2, const float* __restrict__ b2,
    const float* __restrict__ glp, const float* __restrict__ vvec,
    const float* __restrict__ gwt,
    float* __restrict__ out_adj, uint4* __restrict__ zb4)
{
    const int bd = blockIdx.x;
    const int b  = bd / DD;
    const int d  = bd - b*DD;
    const int t  = threadIdx.x;

    __shared__ float sm[11776];
    const int XS=0, N1=3036, N2=6072, S12=9108, ADJ=9660, XW=10212,
              DEG=11684, DINV=11707, FACT=11730, INFS=11753;
    const int XWP = N1;   // alias (A7 partials; dead before GC reuse)
    const int GC  = N1;   // alias (A8 gcn output)

    const float* xg = x + (size_t)bd * (DN*DF);
    for (int p = t; p < DN*DF; p += 256) {
        int n = p >> 7, f = p & 127;
        sm[XS + n*132 + f] = xg[p];
    }
    if (t < DN) {
        float vv = vvec[t];
        sm[FACT + t] = __expf(vv*vv*(float)day_order[b]);
        sm[INFS + t] = infection[(size_t)bd*DN + t];
    }
    __syncthreads();

    // A2: n1/n2
    {
        const int mat = t >> 7, fo = t & 127;
        const float* wr = (mat ? w2 : w1) + fo*DF;
        const float bias = (mat ? b2 : b1)[fo];
        float acc[DN];
        #pragma unroll
        for (int n=0;n<DN;n++) acc[n]=0.f;
        float4 w4 = *(const float4*)wr;
        for (int k4=0;k4<32;k4++){
            float4 wn = w4;
            if (k4 < 31) wn = *(const float4*)(wr + 4*(k4+1));
            #pragma unroll
            for (int n=0;n<DN;n++){
                float4 xv = *(const float4*)&sm[XS + n*132 + 4*k4];
                acc[n] = FMA4(xv, w4, acc[n]);
            }
            w4 = wn;
        }
        const int dst = mat ? N2 : N1;
        #pragma unroll
        for (int n=0;n<DN;n++) sm[dst + n*132 + fo] = ftanh(acc[n]+bias);
    }
    __syncthreads();

    // A3: s12 + deg
    if (t < DN) {
        const float* ar = adj_real + (size_t)bd*(DN*DN) + t*DN;
        float s = 0.f;
        for (int m=0;m<DN;m++) s += ar[m];
        sm[DEG+t] = s;
    }
    for (int p=t; p<DN*DN; p+=256){
        int i = p/DN, j = p - i*DN;
        float a = 0.f;
        for (int k4=0;k4<32;k4++){
            float4 av = *(const float4*)&sm[N1 + i*132 + 4*k4];
            float4 bv = *(const float4*)&sm[N2 + j*132 + 4*k4];
            a = FMA4(av, bv, a);
        }
        sm[S12 + i*24 + j] = a;
    }
    __syncthreads();

    // A4: adj
    for (int p=t; p<DN*DN; p+=256){
        int i=p/DN, j=p-i*DN;
        float al  = fmaxf(ftanh(sm[S12+i*24+j]-sm[S12+j*24+i]), 0.f);
        float md  = fsig(glp[i*DN+j]*sm[DEG+i]*sm[DEG+j]);
        float arv = adj_real[(size_t)bd*(DN*DN) + p];
        float adjv = al + md*arv;
        __builtin_nontemporal_store(adjv, &out_adj[(size_t)bd*(DN*DN) + p]);
        sm[ADJ + i*24 + j] = adjv + (i==j ? 1.f : 0.f);
    }
    __syncthreads();

    if (t<DN){
        float rs=0.f;
        for (int jj=0;jj<DN;jj++) rs += sm[ADJ+t*24+jj];
        sm[DINV+t] = rsqrtf(rs);
    }
    __syncthreads();
    for (int p=t;p<DN*DN;p+=256){
        int i=p/DN, j=p-i*DN;
        sm[ADJ+i*24+j] *= sm[DINV+i]*sm[DINV+j];
    }
    __syncthreads();

    // A7: xw = x @ gcn_w (k split 4 ways)
    {
        const int o = t & 63, q = t >> 6;
        float acc[DN];
        #pragma unroll
        for (int n=0;n<DN;n++) acc[n]=0.f;
        const float* gw = gwt + o*DF + q*32;
        for (int k4=0;k4<8;k4++){
            float4 w4 = *(const float4*)(gw + 4*k4);
            #pragma unroll
            for (int n=0;n<DN;n++){
                float4 xv = *(const float4*)&sm[XS + n*132 + q*32 + 4*k4];
                acc[n] = FMA4(xv, w4, acc[n]);
            }
        }
        #pragma unroll
        for (int n=0;n<DN;n++) sm[XWP + (q*DN+n)*64 + o] = acc[n];
    }
    __syncthreads();
    for (int p=t;p<DN*64;p+=256){
        int n=p>>6, o=p&63;
        sm[XW+p] = sm[XWP + n*64 + o] + sm[XWP + (DN+n)*64 + o]
                 + sm[XWP + (2*DN+n)*64 + o] + sm[XWP + (3*DN+n)*64 + o];
    }
    __syncthreads();

    // A8: gcn -> GC (factor applied)
    for (int p=t;p<DN*64;p+=256){
        int n=p>>6, o=p&63;
        float a=0.f;
        #pragma unroll
        for (int m=0;m<DN;m++) a = fmaf(sm[ADJ+n*24+m], sm[XW+m*64+o], a);
        sm[GC + p] = fmaxf(a,0.f)*sm[FACT+n];
    }
    __syncthreads();

    // pack: per (n, k8 0..8, hi/lo): 8 elems -> one uint4
    for (int p=t; p<DN*18; p+=256){
        int n = p/18, r = p - n*18, k8 = r>>1, hsel = r&1;
        __align__(16) unsigned short ob[8];
        #pragma unroll
        for (int e=0;e<8;e++){
            int k = k8*8+e;
            float v = (k<64) ? sm[GC + n*64 + k] : ((k==64) ? sm[INFS+n] : 0.f);
            unsigned short hb = f2bf(v);
            ob[e] = hsel ? f2bf(v - bf2f(hb)) : hb;
        }
        int gseq = n*DB + b;
        int blkz = gseq >> 5, seq = gseq & 31;
        zb4[(size_t)(d*GBLK + blkz)*576 + hsel*288 + k8*32 + seq] = *(const uint4*)ob;
    }
}

// ---------------------------------------------------------------------------
// Kernel B: MFMA LSTM.  grid=184, block=512 (8 waves).  Wave w: M-tiles 4w..4w+3.
// Lane: lhi=l>>4 -> local channel, llo=l&15 -> seq within N-tile.
// acc[mi][nt] f32x4: regs = gates (i,f,g,o) of channel j=16w+mi*4+lhi, seq=nt*16+llo.
// Biases live in LDS (BIAS0/BIAS1) -> acc init via broadcast LDS reads.
// launch_bounds(512,1): min 1 wave/EU -> full VGPR budget, no spills.
// ---------------------------------------------------------------------------
#define U0HI 0
#define U0LO 14336
#define U1HI 28672
#define U1LO 45056
#define FCWO 61440
#define INFCO 61956
#define BIAS0 62084
#define BIAS1 64132
// end 66180

__global__ __launch_bounds__(512, 1) void kernB(
    const uint4* __restrict__ zb4, const v8bf* __restrict__ w0p, const v8bf* __restrict__ w1p,
    const float* __restrict__ b0g, const float* __restrict__ b1g,
    const float* __restrict__ infection, const float* __restrict__ fcw,
    const float* __restrict__ fcb, float* __restrict__ outy)
{
    const int t = threadIdx.x, blk = blockIdx.x;
    const int w = t>>6, l = t&63;
    const int lhi = l>>4, llo = l&15;
    __shared__ __align__(16) unsigned char smraw[66192];
    char* smb = (char*)smraw;

    // zero U0/U1 (61440 B)
    for (int i = t; i < 61440/16; i += 512){
        uint4 z; z.x=z.y=z.z=z.w=0u;
        ((uint4*)smraw)[i] = z;
    }
    if (t < 129) ((float*)(smb+FCWO))[t] = (t<128) ? fcw[t] : fcb[0];
    if (t < 32){
        int gseq = blk*32 + t, n = gseq>>8, bb = gseq&255;
        float a = 0.f;
        for (int dd=0; dd<DD; dd++)
            a = fmaf(fcw[128+dd], infection[((size_t)bb*DD+dd)*DN+n], a);
        ((float*)(smb+INFCO))[t] = a;
    }
    ((float*)(smb+BIAS0))[t] = b0g[t];
    ((float*)(smb+BIAS1))[t] = b1g[t];

    float c0[4][2] = {}, c1[4][2] = {};
    float x2r[8];
    #pragma unroll
    for (int e=0;e<8;e++) x2r[e] = 0.f;
    __syncthreads();

    // stage step 0 (x part of U0): unit u = w*72 + i, hi units 0..287, lo 288..575
    {
        const uint4* src = zb4 + (size_t)blk*576;
        int u = w*72 + l;
        uint4 a0 = ntload4(src + u);
        int d0 = (u<288) ? u*16 : (U0LO + (u-288)*16);
        *(uint4*)(smb + d0) = a0;
        if (l < 8){
            int u2 = u + 64;
            uint4 a1 = ntload4(src + u2);
            int d1 = (u2<288) ? u2*16 : (U0LO + (u2-288)*16);
            *(uint4*)(smb + d1) = a1;
        }
    }
    __syncthreads();

    const float* bias0L = (const float*)(smb+BIAS0);
    const float* bias1L = (const float*)(smb+BIAS1);

    for (int step = 0; step < DD + DY; ++step){
        // ---- running input mean (encoder) / build decoder input (step 28)
        if (step < DD){
            if (t < 288){
                uint4 hv = *(const uint4*)(smb + U0HI + t*16);
                uint4 lv = *(const uint4*)(smb + U0LO + t*16);
                const unsigned short* hp = (const unsigned short*)&hv;
                const unsigned short* lp = (const unsigned short*)&lv;
                #pragma unroll
                for (int e=0;e<8;e++) x2r[e] += bf2f(hp[e]) + bf2f(lp[e]);
            }
        } else if (step == DD){
            if (t < 288){
                __align__(16) unsigned short hb8[8], lb8[8];
                #pragma unroll
                for (int e=0;e<8;e++){
                    float v = x2r[e] * (1.f/(float)DD);
                    unsigned short h = f2bf(v);
                    hb8[e] = h;
                    lb8[e] = f2bf(v - bf2f(h));
                }
                *(uint4*)(smb + U0HI + t*16) = *(const uint4*)hb8;
                *(uint4*)(smb + U0LO + t*16) = *(const uint4*)lb8;
            }
            __syncthreads();
        }

        // ---------------- layer 0: G = W0 @ [x|h0], 7 k-tiles ----------------
        {
            f32x4 acc[4][2];
            #pragma unroll
            for (int mi=0;mi<4;mi++){
                int j = 16*w + mi*4 + lhi;
                f32x4 a;
                a[0]=bias0L[j]; a[1]=bias0L[128+j]; a[2]=bias0L[256+j]; a[3]=bias0L[384+j];
                acc[mi][0] = a; acc[mi][1] = a;
            }
            #pragma unroll
            for (int kt=0; kt<7; ++kt){
                const v8bf* wrow = w0p + (size_t)(kt*32 + w*4)*64 + l;
                v8bf A0 = wrow[0], A1 = wrow[64], A2 = wrow[128], A3 = wrow[192];
                int bu = (kt*4 + lhi)*32 + llo;
                v8bf BH0 = *(const v8bf*)(smb + U0HI + bu*16);
                v8bf BH1 = *(const v8bf*)(smb + U0HI + (bu+16)*16);
                v8bf BL0 = *(const v8bf*)(smb + U0LO + bu*16);
                v8bf BL1 = *(const v8bf*)(smb + U0LO + (bu+16)*16);
                MFMA_(acc[0][0], A0, BH0); MFMA_(acc[0][0], A0, BL0);
                MFMA_(acc[1][0], A1, BH0); MFMA_(acc[1][0], A1, BL0);
                MFMA_(acc[2][0], A2, BH0); MFMA_(acc[2][0], A2, BL0);
                MFMA_(acc[3][0], A3, BH0); MFMA_(acc[3][0], A3, BL0);
                MFMA_(acc[0][1], A0, BH1); MFMA_(acc[0][1], A0, BL1);
                MFMA_(acc[1][1], A1, BH1); MFMA_(acc[1][1], A1, BL1);
                MFMA_(acc[2][1], A2, BH1); MFMA_(acc[2][1], A2, BL1);
                MFMA_(acc[3][1], A3, BH1); MFMA_(acc[3][1], A3, BL1);
            }
            __syncthreads();   // B2: all U0 reads done

            // issue next-step x loads (written to LDS after L1)
            uint4 sv0, sv1; sv0.x=sv0.y=sv0.z=sv0.w=0u; sv1 = sv0;
            const bool do_stage = (step + 1 < DD);
            if (do_stage){
                const uint4* src = zb4 + (size_t)((step+1)*GBLK + blk)*576;
                sv0 = ntload4(src + w*72 + l);
                if (l < 8) sv1 = ntload4(src + w*72 + 64 + l);
            }

            // activation L0 + h0 writes (U0 h-region + U1 h0-region)
            #pragma unroll
            for (int mi=0;mi<4;mi++){
                int j = 16*w + mi*4 + lhi;
                int j8 = j>>3, je = j&7;
                #pragma unroll
                for (int nt=0;nt<2;nt++){
                    f32x4 a = acc[mi][nt];
                    float ii = fsig(a[0]), ff = fsig(a[1]), gg = ftanh(a[2]), oo = fsig(a[3]);
                    float c = ff*c0[mi][nt] + ii*gg;  c0[mi][nt] = c;
                    float h = oo*ftanh(c);
                    unsigned short hb = f2bf(h);
                    unsigned short lb = f2bf(h - bf2f(hb));
                    int seq = nt*16 + llo;
                    ((unsigned short*)(smb+U0HI))[((9+j8)*32+seq)*8 + je] = hb;
                    ((unsigned short*)(smb+U0LO))[((9+j8)*32+seq)*8 + je] = lb;
                    ((unsigned short*)(smb+U1HI))[(j8*32+seq)*8 + je]     = hb;
                    ((unsigned short*)(smb+U1LO))[(j8*32+seq)*8 + je]     = lb;
                }
            }
            __syncthreads();   // B3: h0 visible

            // ---------------- layer 1: G = W1 @ [h0|h1], 8 k-tiles ----------------
            f32x4 acc1[4][2];
            #pragma unroll
            for (int mi=0;mi<4;mi++){
                int j = 16*w + mi*4 + lhi;
                f32x4 a;
                a[0]=bias1L[j]; a[1]=bias1L[128+j]; a[2]=bias1L[256+j]; a[3]=bias1L[384+j];
                acc1[mi][0] = a; acc1[mi][1] = a;
            }
            #pragma unroll
            for (int kt=0; kt<8; ++kt){
                const v8bf* wrow = w1p + (size_t)(kt*32 + w*4)*64 + l;
                v8bf A0 = wrow[0], A1 = wrow[64], A2 = wrow[128], A3 = wrow[192];
                int bu = (kt*4 + lhi)*32 + llo;
                v8bf BH0 = *(const v8bf*)(smb + U1HI + bu*16);
                v8bf BH1 = *(const v8bf*)(smb + U1HI + (bu+16)*16);
                v8bf BL0 = *(const v8bf*)(smb + U1LO + bu*16);
                v8bf BL1 = *(const v8bf*)(smb + U1LO + (bu+16)*16);
                MFMA_(acc1[0][0], A0, BH0); MFMA_(acc1[0][0], A0, BL0);
                MFMA_(acc1[1][0], A1, BH0); MFMA_(acc1[1][0], A1, BL0);
                MFMA_(acc1[2][0], A2, BH0); MFMA_(acc1[2][0], A2, BL0);
                MFMA_(acc1[3][0], A3, BH0); MFMA_(acc1[3][0], A3, BL0);
                MFMA_(acc1[0][1], A0, BH1); MFMA_(acc1[0][1], A0, BL1);
                MFMA_(acc1[1][1], A1, BH1); MFMA_(acc1[1][1], A1, BL1);
                MFMA_(acc1[2][1], A2, BH1); MFMA_(acc1[2][1], A2, BL1);
                MFMA_(acc1[3][1], A3, BH1); MFMA_(acc1[3][1], A3, BL1);
            }
            __syncthreads();   // B4: all U1 reads done

            if (do_stage){
                int u = w*72 + l;
                int d0 = (u<288) ? u*16 : (U0LO + (u-288)*16);
                *(uint4*)(smb + d0) = sv0;
                if (l < 8){
                    int u2 = u + 64;
                    int d1 = (u2<288) ? u2*16 : (U0LO + (u2-288)*16);
                    *(uint4*)(smb + d1) = sv1;
                }
            }

            // activation L1 + h1 writes
            #pragma unroll
            for (int mi=0;mi<4;mi++){
                int j = 16*w + mi*4 + lhi;
                int j8 = j>>3, je = j&7;
                #pragma unroll
                for (int nt=0;nt<2;nt++){
                    f32x4 a = acc1[mi][nt];
                    float ii = fsig(a[0]), ff = fsig(a[1]), gg = ftanh(a[2]), oo = fsig(a[3]);
                    float c = ff*c1[mi][nt] + ii*gg;  c1[mi][nt] = c;
                    float h = oo*ftanh(c);
                    unsigned short hb = f2bf(h);
                    unsigned short lb = f2bf(h - bf2f(hb));
                    int seq = nt*16 + llo;
                    ((unsigned short*)(smb+U1HI))[((16+j8)*32+seq)*8 + je] = hb;
                    ((unsigned short*)(smb+U1LO))[((16+j8)*32+seq)*8 + je] = lb;
                }
            }
        }

        // ---- decoder FC
        if (step >= DD){
            __syncthreads();   // h1 visible
            if (t < 256){
                int seq = t>>3, l8 = t&7;
                const unsigned short* uh = (const unsigned short*)(smb+U1HI);
                const unsigned short* ul = (const unsigned short*)(smb+U1LO);
                const float* fw = (const float*)(smb+FCWO);
                float a = 0.f;
                #pragma unroll
                for (int half=0; half<2; ++half){
                    int k8 = 16 + l8*2 + half;
                    int base = (k8*32 + seq)*8;
                    #pragma unroll
                    for (int e=0;e<8;e++){
                        int j = l8*16 + half*8 + e;
                        a = fmaf(fw[j], bf2f(uh[base+e]) + bf2f(ul[base+e]), a);
                    }
                }
                a += __shfl_down(a, 4, 8);
                a += __shfl_down(a, 2, 8);
                a += __shfl_down(a, 1, 8);
                if (l8 == 0){
                    int gseq = blk*32 + seq, n = gseq>>8, bb = gseq&255;
                    float yv = fmaxf(a + ((const float*)(smb+INFCO))[seq] + fw[128], 0.f);
                    __builtin_nontemporal_store(yv, &outy[((size_t)bb*DY + (step-DD))*DN + n]);
                }
            }
        }
        __syncthreads();   // close step (staging writes / FC reads before next iter)
    }
}

// ---------------------------------------------------------------------------
extern "C" void kernel_launch(void* const* d_in, const int* in_sizes, int n_in,
                              void* d_out, int out_size, void* d_ws, size_t ws_size,
                              hipStream_t stream)
{
    const float* x         = (const float*)d_in[0];
    const float* adj_real  = (const float*)d_in[1];
    const float* infection = (const float*)d_in[2];
    const int*   day_order = (const int*)  d_in[3];
    const float* gl_w1     = (const float*)d_in[4];
    const float* gl_b1     = (const float*)d_in[5];
    const float* gl_w2     = (const float*)d_in[6];
    const float* gl_b2     = (const float*)d_in[7];
    const float* glp       = (const float*)d_in[8];
    const float* gcn_w     = (const float*)d_in[9];
    const float* vvec      = (const float*)d_in[10];
    const float* wih0      = (const float*)d_in[11];
    const float* whh0      = (const float*)d_in[12];
    const float* b0        = (const float*)d_in[13];
    const float* wih1      = (const float*)d_in[14];
    const float* whh1      = (const float*)d_in[15];
    const float* b1        = (const float*)d_in[16];
    const float* fcw       = (const float*)d_in[17];
    const float* fcb       = (const float*)d_in[18];

    uint8_t* wsb = (uint8_t*)d_ws;
    unsigned short* zb  = (unsigned short*)(wsb);
    unsigned short* wb0 = (unsigned short*)(wsb + WB0_OFF);
    unsigned short* wb1 = (unsigned short*)(wsb + WB1_OFF);
    float*          gwt = (float*)(wsb + GWT_OFFB);
    float* out_adj = (float*)d_out;
    float* out_y   = out_adj + ADJSZ;

    kernPrep<<<dim3(992), dim3(256), 0, stream>>>(wih0, whh0, wih1, whh1, gcn_w,
                                                  wb0, wb1, gwt);
    kernA<<<dim3(DB*DD), dim3(256), 0, stream>>>(x, adj_real, infection, day_order,
                                                 gl_w1, gl_b1, gl_w2, gl_b2, glp,
                                                 vvec, gwt, out_adj, (uint4*)zb);
    kernB<<<dim3(GBLK), dim3(512), 0, stream>>>((const uint4*)zb, (const v8bf*)wb0,
                                                (const v8bf*)wb1, b0, b1, infection,
                                                fcw, fcb, out_y);
}

// Round 5
// 909.015 us; speedup vs baseline: 2.4096x; 1.0008x over previous
//
#include <hip/hip_runtime.h>
#include <hip/hip_bf16.h>
#include <stdint.h>

// ---------------------------------------------------------------------------
// B=256 D=28 N=23 F=128 O=64 H=128 Y=7.  NBSEQ=5888 = 184 blocks x 32 seqs.
// kernPrep: pack W (bf16, MFMA-A fragment order, gate-grouped rows) + gwt.
// kernA   : per-(b,d) graph stage -> adj (out0) + zin packed bf16 hi/lo in
//           MFMA-B layout [step][blk184][k8 0..8][hi/lo][seq32][8e].
// kernB   : 2-layer LSTM via mfma_f32_16x16x32_bf16, U split hi+lo, W single
//           bf16 streamed from L2; gates of a channel live in one lane.
// R5: VGPR cap was the spill cause: backend targeted 4 waves/SIMD (LDS-derived)
//     -> 128-reg cap regardless of launch_bounds min. Pin with
//     amdgpu_waves_per_eu(2,2) (-> 256-reg budget) + LDS pad > 80KB so the
//     LDS occupancy limit agrees (1 block/CU; free since grid 184 <= 256 CUs).
// ---------------------------------------------------------------------------

#define DB 256
#define DD 28
#define DN 23
#define DF 128
#define DO 64
#define DH 128
#define DY 7
#define NBSEQ (DN*DB)
#define ADJSZ (DB*DD*DN*DN)
#define GBLK 184

// workspace byte offsets
#define ZB_BYTES  47480832u            // 28*184*576*16
#define WB0_OFF   47480832u            // 7*32*64*8*2  = 229376
#define WB1_OFF   47710208u            // 8*32*64*8*2  = 262144
#define GWT_OFFB  47972352u            // 8192 f32

using v8bf  = __attribute__((ext_vector_type(8))) __bf16;
using f32x4 = __attribute__((ext_vector_type(4))) float;
using u32x4 = __attribute__((ext_vector_type(4))) unsigned int;

__device__ __forceinline__ float fsig(float x)  { return 1.f/(1.f+__expf(-x)); }
__device__ __forceinline__ float ftanh(float x) { return 1.f - 2.f/(__expf(2.f*x)+1.f); }

__device__ __forceinline__ unsigned short f2bf(float f){
    unsigned u = __builtin_bit_cast(unsigned, f);
    return (unsigned short)((u + 0x7FFFu + ((u>>16)&1u)) >> 16);
}
__device__ __forceinline__ float bf2f(unsigned short b){
    return __builtin_bit_cast(float, (unsigned)b << 16);
}
__device__ __forceinline__ uint4 ntload4(const uint4* p){
    u32x4 v = __builtin_nontemporal_load((const u32x4*)p);
    return *(uint4*)&v;
}

#define FMA4(xv, wv, a) fmaf((xv).w,(wv).w, fmaf((xv).z,(wv).z, fmaf((xv).y,(wv).y, fmaf((xv).x,(wv).x,(a)))))
#define MFMA_(acc_, A_, B_) acc_ = __builtin_amdgcn_mfma_f32_16x16x32_bf16(A_, B_, acc_, 0, 0, 0)

// ---------------------------------------------------------------------------
// Prep. Wb[kt][mt][lane][e]: A-frag row rit=lane&15 -> (localj=rit>>2, g=rit&3),
// orig row r = g*128 + mt*4 + localj; k = kt*32 + (lane>>4)*8 + e.
// L0 cols: k<65 -> wih0 ; 72<=k<200 -> whh0[k-72] ; else 0.  (x padded to 72)
// L1 cols: k<128 -> wih1 ; else whh1[k-128].
// ---------------------------------------------------------------------------
__global__ __launch_bounds__(256) void kernPrep(
    const float* __restrict__ wih0, const float* __restrict__ whh0,
    const float* __restrict__ wih1, const float* __restrict__ whh1,
    const float* __restrict__ gcn_w,
    unsigned short* __restrict__ wb0, unsigned short* __restrict__ wb1,
    float* __restrict__ gwt)
{
    int idx = blockIdx.x*256 + threadIdx.x;
    if (idx < 114688){
        int e = idx&7, l = (idx>>3)&63, mt = (idx>>9)&31, kt = idx>>14;
        int rit = l&15, lj = rit>>2, g = rit&3;
        int r = g*128 + mt*4 + lj;
        int k = kt*32 + (l>>4)*8 + e;
        float v = 0.f;
        if (k < 65)                 v = wih0[r*65 + k];
        else if (k >= 72 && k < 200) v = whh0[r*128 + (k-72)];
        wb0[idx] = f2bf(v);
        return;
    }
    idx -= 114688;
    if (idx < 131072){
        int e = idx&7, l = (idx>>3)&63, mt = (idx>>9)&31, kt = idx>>14;
        int rit = l&15, lj = rit>>2, g = rit&3;
        int r = g*128 + mt*4 + lj;
        int k = kt*32 + (l>>4)*8 + e;
        float v = (k < 128) ? wih1[r*128 + k] : whh1[r*128 + (k-128)];
        wb1[idx] = f2bf(v);
        return;
    }
    idx -= 131072;
    if (idx < 8192){
        int o = idx >> 7, f = idx & 127;
        gwt[idx] = gcn_w[f*DO + o];     // gwt[o][f]
    }
}

// ---------------------------------------------------------------------------
// Kernel A: per-(b,d) graph stage.  grid = 7168, block = 256.
// ---------------------------------------------------------------------------
__global__ __launch_bounds__(256) void kernA(
    const float* __restrict__ x, const float* __restrict__ adj_real,
    const float* __restrict__ infection, const int* __restrict__ day_order,
    const float* __restrict__ w1, const float* __restrict__ b1,
    const float* __restrict__ w2, const float* __restrict__ b2,
    const float* __restrict__ glp, const float* __restrict__ vvec,
    const float* __restrict__ gwt,
    float* __restrict__ out_adj, uint4* __restrict__ zb4)
{
    const int bd = blockIdx.x;
    const int b  = bd / DD;
    const int d  = bd - b*DD;
    const int t  = threadIdx.x;

    __shared__ float sm[11776];
    const int XS=0, N1=3036, N2=6072, S12=9108, ADJ=9660, XW=10212,
              DEG=11684, DINV=11707, FACT=11730, INFS=11753;
    const int XWP = N1;   // alias (A7 partials; dead before GC reuse)
    const int GC  = N1;   // alias (A8 gcn output)

    const float* xg = x + (size_t)bd * (DN*DF);
    for (int p = t; p < DN*DF; p += 256) {
        int n = p >> 7, f = p & 127;
        sm[XS + n*132 + f] = xg[p];
    }
    if (t < DN) {
        float vv = vvec[t];
        sm[FACT + t] = __expf(vv*vv*(float)day_order[b]);
        sm[INFS + t] = infection[(size_t)bd*DN + t];
    }
    __syncthreads();

    // A2: n1/n2
    {
        const int mat = t >> 7, fo = t & 127;
        const float* wr = (mat ? w2 : w1) + fo*DF;
        const float bias = (mat ? b2 : b1)[fo];
        float acc[DN];
        #pragma unroll
        for (int n=0;n<DN;n++) acc[n]=0.f;
        float4 w4 = *(const float4*)wr;
        for (int k4=0;k4<32;k4++){
            float4 wn = w4;
            if (k4 < 31) wn = *(const float4*)(wr + 4*(k4+1));
            #pragma unroll
            for (int n=0;n<DN;n++){
                float4 xv = *(const float4*)&sm[XS + n*132 + 4*k4];
                acc[n] = FMA4(xv, w4, acc[n]);
            }
            w4 = wn;
        }
        const int dst = mat ? N2 : N1;
        #pragma unroll
        for (int n=0;n<DN;n++) sm[dst + n*132 + fo] = ftanh(acc[n]+bias);
    }
    __syncthreads();

    // A3: s12 + deg
    if (t < DN) {
        const float* ar = adj_real + (size_t)bd*(DN*DN) + t*DN;
        float s = 0.f;
        for (int m=0;m<DN;m++) s += ar[m];
        sm[DEG+t] = s;
    }
    for (int p=t; p<DN*DN; p+=256){
        int i = p/DN, j = p - i*DN;
        float a = 0.f;
        for (int k4=0;k4<32;k4++){
            float4 av = *(const float4*)&sm[N1 + i*132 + 4*k4];
            float4 bv = *(const float4*)&sm[N2 + j*132 + 4*k4];
            a = FMA4(av, bv, a);
        }
        sm[S12 + i*24 + j] = a;
    }
    __syncthreads();

    // A4: adj
    for (int p=t; p<DN*DN; p+=256){
        int i=p/DN, j=p-i*DN;
        float al  = fmaxf(ftanh(sm[S12+i*24+j]-sm[S12+j*24+i]), 0.f);
        float md  = fsig(glp[i*DN+j]*sm[DEG+i]*sm[DEG+j]);
        float arv = adj_real[(size_t)bd*(DN*DN) + p];
        float adjv = al + md*arv;
        __builtin_nontemporal_store(adjv, &out_adj[(size_t)bd*(DN*DN) + p]);
        sm[ADJ + i*24 + j] = adjv + (i==j ? 1.f : 0.f);
    }
    __syncthreads();

    if (t<DN){
        float rs=0.f;
        for (int jj=0;jj<DN;jj++) rs += sm[ADJ+t*24+jj];
        sm[DINV+t] = rsqrtf(rs);
    }
    __syncthreads();
    for (int p=t;p<DN*DN;p+=256){
        int i=p/DN, j=p-i*DN;
        sm[ADJ+i*24+j] *= sm[DINV+i]*sm[DINV+j];
    }
    __syncthreads();

    // A7: xw = x @ gcn_w (k split 4 ways)
    {
        const int o = t & 63, q = t >> 6;
        float acc[DN];
        #pragma unroll
        for (int n=0;n<DN;n++) acc[n]=0.f;
        const float* gw = gwt + o*DF + q*32;
        for (int k4=0;k4<8;k4++){
            float4 w4 = *(const float4*)(gw + 4*k4);
            #pragma unroll
            for (int n=0;n<DN;n++){
                float4 xv = *(const float4*)&sm[XS + n*132 + q*32 + 4*k4];
                acc[n] = FMA4(xv, w4, acc[n]);
            }
        }
        #pragma unroll
        for (int n=0;n<DN;n++) sm[XWP + (q*DN+n)*64 + o] = acc[n];
    }
    __syncthreads();
    for (int p=t;p<DN*64;p+=256){
        int n=p>>6, o=p&63;
        sm[XW+p] = sm[XWP + n*64 + o] + sm[XWP + (DN+n)*64 + o]
                 + sm[XWP + (2*DN+n)*64 + o] + sm[XWP + (3*DN+n)*64 + o];
    }
    __syncthreads();

    // A8: gcn -> GC (factor applied)
    for (int p=t;p<DN*64;p+=256){
        int n=p>>6, o=p&63;
        float a=0.f;
        #pragma unroll
        for (int m=0;m<DN;m++) a = fmaf(sm[ADJ+n*24+m], sm[XW+m*64+o], a);
        sm[GC + p] = fmaxf(a,0.f)*sm[FACT+n];
    }
    __syncthreads();

    // pack: per (n, k8 0..8, hi/lo): 8 elems -> one uint4
    for (int p=t; p<DN*18; p+=256){
        int n = p/18, r = p - n*18, k8 = r>>1, hsel = r&1;
        __align__(16) unsigned short ob[8];
        #pragma unroll
        for (int e=0;e<8;e++){
            int k = k8*8+e;
            float v = (k<64) ? sm[GC + n*64 + k] : ((k==64) ? sm[INFS+n] : 0.f);
            unsigned short hb = f2bf(v);
            ob[e] = hsel ? f2bf(v - bf2f(hb)) : hb;
        }
        int gseq = n*DB + b;
        int blkz = gseq >> 5, seq = gseq & 31;
        zb4[(size_t)(d*GBLK + blkz)*576 + hsel*288 + k8*32 + seq] = *(const uint4*)ob;
    }
}

// ---------------------------------------------------------------------------
// Kernel B: MFMA LSTM.  grid=184, block=512 (8 waves).  Wave w: M-tiles 4w..4w+3.
// Lane: lhi=l>>4 -> local channel, llo=l&15 -> seq within N-tile.
// acc[mi][nt] f32x4: regs = gates (i,f,g,o) of channel j=16w+mi*4+lhi, seq=nt*16+llo.
// Biases in LDS.  amdgpu_waves_per_eu(2,2) -> 256-VGPR budget (kill spills);
// LDS padded >80KB so LDS occupancy limit = 1 block/CU agrees (free: grid 184).
// ---------------------------------------------------------------------------
#define U0HI 0
#define U0LO 14336
#define U1HI 28672
#define U1LO 45056
#define FCWO 61440
#define INFCO 61956
#define BIAS0 62084
#define BIAS1 64132
// data end 66180; pad to 84000 to force 1 block/CU occupancy target

__global__ __attribute__((amdgpu_flat_work_group_size(512,512), amdgpu_waves_per_eu(2,2)))
void kernB(
    const uint4* __restrict__ zb4, const v8bf* __restrict__ w0p, const v8bf* __restrict__ w1p,
    const float* __restrict__ b0g, const float* __restrict__ b1g,
    const float* __restrict__ infection, const float* __restrict__ fcw,
    const float* __restrict__ fcb, float* __restrict__ outy)
{
    const int t = threadIdx.x, blk = blockIdx.x;
    const int w = t>>6, l = t&63;
    const int lhi = l>>4, llo = l&15;
    __shared__ __align__(16) unsigned char smraw[84000];
    char* smb = (char*)smraw;

    // zero U0/U1 (61440 B)
    for (int i = t; i < 61440/16; i += 512){
        uint4 z; z.x=z.y=z.z=z.w=0u;
        ((uint4*)smraw)[i] = z;
    }
    if (t < 129) ((float*)(smb+FCWO))[t] = (t<128) ? fcw[t] : fcb[0];
    if (t < 32){
        int gseq = blk*32 + t, n = gseq>>8, bb = gseq&255;
        float a = 0.f;
        for (int dd=0; dd<DD; dd++)
            a = fmaf(fcw[128+dd], infection[((size_t)bb*DD+dd)*DN+n], a);
        ((float*)(smb+INFCO))[t] = a;
    }
    ((float*)(smb+BIAS0))[t] = b0g[t];
    ((float*)(smb+BIAS1))[t] = b1g[t];

    float c0[4][2] = {}, c1[4][2] = {};
    float x2r[8];
    #pragma unroll
    for (int e=0;e<8;e++) x2r[e] = 0.f;
    __syncthreads();

    // stage step 0 (x part of U0): unit u = w*72 + i, hi units 0..287, lo 288..575
    {
        const uint4* src = zb4 + (size_t)blk*576;
        int u = w*72 + l;
        uint4 a0 = ntload4(src + u);
        int d0 = (u<288) ? u*16 : (U0LO + (u-288)*16);
        *(uint4*)(smb + d0) = a0;
        if (l < 8){
            int u2 = u + 64;
            uint4 a1 = ntload4(src + u2);
            int d1 = (u2<288) ? u2*16 : (U0LO + (u2-288)*16);
            *(uint4*)(smb + d1) = a1;
        }
    }
    __syncthreads();

    const float* bias0L = (const float*)(smb+BIAS0);
    const float* bias1L = (const float*)(smb+BIAS1);

    for (int step = 0; step < DD + DY; ++step){
        // ---- running input mean (encoder) / build decoder input (step 28)
        if (step < DD){
            if (t < 288){
                uint4 hv = *(const uint4*)(smb + U0HI + t*16);
                uint4 lv = *(const uint4*)(smb + U0LO + t*16);
                const unsigned short* hp = (const unsigned short*)&hv;
                const unsigned short* lp = (const unsigned short*)&lv;
                #pragma unroll
                for (int e=0;e<8;e++) x2r[e] += bf2f(hp[e]) + bf2f(lp[e]);
            }
        } else if (step == DD){
            if (t < 288){
                __align__(16) unsigned short hb8[8], lb8[8];
                #pragma unroll
                for (int e=0;e<8;e++){
                    float v = x2r[e] * (1.f/(float)DD);
                    unsigned short h = f2bf(v);
                    hb8[e] = h;
                    lb8[e] = f2bf(v - bf2f(h));
                }
                *(uint4*)(smb + U0HI + t*16) = *(const uint4*)hb8;
                *(uint4*)(smb + U0LO + t*16) = *(const uint4*)lb8;
            }
            __syncthreads();
        }

        // ---------------- layer 0: G = W0 @ [x|h0], 7 k-tiles ----------------
        {
            f32x4 acc[4][2];
            #pragma unroll
            for (int mi=0;mi<4;mi++){
                int j = 16*w + mi*4 + lhi;
                f32x4 a;
                a[0]=bias0L[j]; a[1]=bias0L[128+j]; a[2]=bias0L[256+j]; a[3]=bias0L[384+j];
                acc[mi][0] = a; acc[mi][1] = a;
            }
            #pragma unroll
            for (int kt=0; kt<7; ++kt){
                const v8bf* wrow = w0p + (size_t)(kt*32 + w*4)*64 + l;
                v8bf A0 = wrow[0], A1 = wrow[64], A2 = wrow[128], A3 = wrow[192];
                int bu = (kt*4 + lhi)*32 + llo;
                v8bf BH0 = *(const v8bf*)(smb + U0HI + bu*16);
                v8bf BH1 = *(const v8bf*)(smb + U0HI + (bu+16)*16);
                v8bf BL0 = *(const v8bf*)(smb + U0LO + bu*16);
                v8bf BL1 = *(const v8bf*)(smb + U0LO + (bu+16)*16);
                MFMA_(acc[0][0], A0, BH0); MFMA_(acc[0][0], A0, BL0);
                MFMA_(acc[1][0], A1, BH0); MFMA_(acc[1][0], A1, BL0);
                MFMA_(acc[2][0], A2, BH0); MFMA_(acc[2][0], A2, BL0);
                MFMA_(acc[3][0], A3, BH0); MFMA_(acc[3][0], A3, BL0);
                MFMA_(acc[0][1], A0, BH1); MFMA_(acc[0][1], A0, BL1);
                MFMA_(acc[1][1], A1, BH1); MFMA_(acc[1][1], A1, BL1);
                MFMA_(acc[2][1], A2, BH1); MFMA_(acc[2][1], A2, BL1);
                MFMA_(acc[3][1], A3, BH1); MFMA_(acc[3][1], A3, BL1);
            }
            __syncthreads();   // B2: all U0 reads done

            // issue next-step x loads (written to LDS after L1)
            uint4 sv0, sv1; sv0.x=sv0.y=sv0.z=sv0.w=0u; sv1 = sv0;
            const bool do_stage = (step + 1 < DD);
            if (do_stage){
                const uint4* src = zb4 + (size_t)((step+1)*GBLK + blk)*576;
                sv0 = ntload4(src + w*72 + l);
                if (l < 8) sv1 = ntload4(src + w*72 + 64 + l);
            }

            // activation L0 + h0 writes (U0 h-region + U1 h0-region)
            #pragma unroll
            for (int mi=0;mi<4;mi++){
                int j = 16*w + mi*4 + lhi;
                int j8 = j>>3, je = j&7;
                #pragma unroll
                for (int nt=0;nt<2;nt++){
                    f32x4 a = acc[mi][nt];
                    float ii = fsig(a[0]), ff = fsig(a[1]), gg = ftanh(a[2]), oo = fsig(a[3]);
                    float c = ff*c0[mi][nt] + ii*gg;  c0[mi][nt] = c;
                    float h = oo*ftanh(c);
                    unsigned short hb = f2bf(h);
                    unsigned short lb = f2bf(h - bf2f(hb));
                    int seq = nt*16 + llo;
                    ((unsigned short*)(smb+U0HI))[((9+j8)*32+seq)*8 + je] = hb;
                    ((unsigned short*)(smb+U0LO))[((9+j8)*32+seq)*8 + je] = lb;
                    ((unsigned short*)(smb+U1HI))[(j8*32+seq)*8 + je]     = hb;
                    ((unsigned short*)(smb+U1LO))[(j8*32+seq)*8 + je]     = lb;
                }
            }
            __syncthreads();   // B3: h0 visible

            // ---------------- layer 1: G = W1 @ [h0|h1], 8 k-tiles ----------------
            f32x4 acc1[4][2];
            #pragma unroll
            for (int mi=0;mi<4;mi++){
                int j = 16*w + mi*4 + lhi;
                f32x4 a;
                a[0]=bias1L[j]; a[1]=bias1L[128+j]; a[2]=bias1L[256+j]; a[3]=bias1L[384+j];
                acc1[mi][0] = a; acc1[mi][1] = a;
            }
            #pragma unroll
            for (int kt=0; kt<8; ++kt){
                const v8bf* wrow = w1p + (size_t)(kt*32 + w*4)*64 + l;
                v8bf A0 = wrow[0], A1 = wrow[64], A2 = wrow[128], A3 = wrow[192];
                int bu = (kt*4 + lhi)*32 + llo;
                v8bf BH0 = *(const v8bf*)(smb + U1HI + bu*16);
                v8bf BH1 = *(const v8bf*)(smb + U1HI + (bu+16)*16);
                v8bf BL0 = *(const v8bf*)(smb + U1LO + bu*16);
                v8bf BL1 = *(const v8bf*)(smb + U1LO + (bu+16)*16);
                MFMA_(acc1[0][0], A0, BH0); MFMA_(acc1[0][0], A0, BL0);
                MFMA_(acc1[1][0], A1, BH0); MFMA_(acc1[1][0], A1, BL0);
                MFMA_(acc1[2][0], A2, BH0); MFMA_(acc1[2][0], A2, BL0);
                MFMA_(acc1[3][0], A3, BH0); MFMA_(acc1[3][0], A3, BL0);
                MFMA_(acc1[0][1], A0, BH1); MFMA_(acc1[0][1], A0, BL1);
                MFMA_(acc1[1][1], A1, BH1); MFMA_(acc1[1][1], A1, BL1);
                MFMA_(acc1[2][1], A2, BH1); MFMA_(acc1[2][1], A2, BL1);
                MFMA_(acc1[3][1], A3, BH1); MFMA_(acc1[3][1], A3, BL1);
            }
            __syncthreads();   // B4: all U1 reads done

            if (do_stage){
                int u = w*72 + l;
                int d0 = (u<288) ? u*16 : (U0LO + (u-288)*16);
                *(uint4*)(smb + d0) = sv0;
                if (l < 8){
                    int u2 = u + 64;
                    int d1 = (u2<288) ? u2*16 : (U0LO + (u2-288)*16);
                    *(uint4*)(smb + d1) = sv1;
                }
            }

            // activation L1 + h1 writes
            #pragma unroll
            for (int mi=0;mi<4;mi++){
                int j = 16*w + mi*4 + lhi;
                int j8 = j>>3, je = j&7;
                #pragma unroll
                for (int nt=0;nt<2;nt++){
                    f32x4 a = acc1[mi][nt];
                    float ii = fsig(a[0]), ff = fsig(a[1]), gg = ftanh(a[2]), oo = fsig(a[3]);
                    float c = ff*c1[mi][nt] + ii*gg;  c1[mi][nt] = c;
                    float h = oo*ftanh(c);
                    unsigned short hb = f2bf(h);
                    unsigned short lb = f2bf(h - bf2f(hb));
                    int seq = nt*16 + llo;
                    ((unsigned short*)(smb+U1HI))[((16+j8)*32+seq)*8 + je] = hb;
                    ((unsigned short*)(smb+U1LO))[((16+j8)*32+seq)*8 + je] = lb;
                }
            }
        }

        // ---- decoder FC
        if (step >= DD){
            __syncthreads();   // h1 visible
            if (t < 256){
                int seq = t>>3, l8 = t&7;
                const unsigned short* uh = (const unsigned short*)(smb+U1HI);
                const unsigned short* ul = (const unsigned short*)(smb+U1LO);
                const float* fw = (const float*)(smb+FCWO);
                float a = 0.f;
                #pragma unroll
                for (int half=0; half<2; ++half){
                    int k8 = 16 + l8*2 + half;
                    int base = (k8*32 + seq)*8;
                    #pragma unroll
                    for (int e=0;e<8;e++){
                        int j = l8*16 + half*8 + e;
                        a = fmaf(fw[j], bf2f(uh[base+e]) + bf2f(ul[base+e]), a);
                    }
                }
                a += __shfl_down(a, 4, 8);
                a += __shfl_down(a, 2, 8);
                a += __shfl_down(a, 1, 8);
                if (l8 == 0){
                    int gseq = blk*32 + seq, n = gseq>>8, bb = gseq&255;
                    float yv = fmaxf(a + ((const float*)(smb+INFCO))[seq] + fw[128], 0.f);
                    __builtin_nontemporal_store(yv, &outy[((size_t)bb*DY + (step-DD))*DN + n]);
                }
            }
        }
        __syncthreads();   // close step (staging writes / FC reads before next iter)
    }
}

// ---------------------------------------------------------------------------
extern "C" void kernel_launch(void* const* d_in, const int* in_sizes, int n_in,
                              void* d_out, int out_size, void* d_ws, size_t ws_size,
                              hipStream_t stream)
{
    const float* x         = (const float*)d_in[0];
    const float* adj_real  = (const float*)d_in[1];
    const float* infection = (const float*)d_in[2];
    const int*   day_order = (const int*)  d_in[3];
    const float* gl_w1     = (const float*)d_in[4];
    const float* gl_b1     = (const float*)d_in[5];
    const float* gl_w2     = (const float*)d_in[6];
    const float* gl_b2     = (const float*)d_in[7];
    const float* glp       = (const float*)d_in[8];
    const float* gcn_w     = (const float*)d_in[9];
    const float* vvec      = (const float*)d_in[10];
    const float* wih0      = (const float*)d_in[11];
    const float* whh0      = (const float*)d_in[12];
    const float* b0        = (const float*)d_in[13];
    const float* wih1      = (const float*)d_in[14];
    const float* whh1      = (const float*)d_in[15];
    const float* b1        = (const float*)d_in[16];
    const float* fcw       = (const float*)d_in[17];
    const float* fcb       = (const float*)d_in[18];

    uint8_t* wsb = (uint8_t*)d_ws;
    unsigned short* zb  = (unsigned short*)(wsb);
    unsigned short* wb0 = (unsigned short*)(wsb + WB0_OFF);
    unsigned short* wb1 = (unsigned short*)(wsb + WB1_OFF);
    float*          gwt = (float*)(wsb + GWT_OFFB);
    float* out_adj = (float*)d_out;
    float* out_y   = out_adj + ADJSZ;

    kernPrep<<<dim3(992), dim3(256), 0, stream>>>(wih0, whh0, wih1, whh1, gcn_w,
                                                  wb0, wb1, gwt);
    kernA<<<dim3(DB*DD), dim3(256), 0, stream>>>(x, adj_real, infection, day_order,
                                                 gl_w1, gl_b1, gl_w2, gl_b2, glp,
                                                 vvec, gwt, out_adj, (uint4*)zb);
    kernB<<<dim3(GBLK), dim3(512), 0, stream>>>((const uint4*)zb, (const v8bf*)wb0,
                                                (const v8bf*)wb1, b0, b1, infection,
                                                fcw, fcb, out_y);
}

// Round 6
// 842.837 us; speedup vs baseline: 2.5988x; 1.0785x over previous
//
#include <hip/hip_runtime.h>
#include <hip/hip_bf16.h>
#include <stdint.h>

// ---------------------------------------------------------------------------
// B=256 D=28 N=23 F=128 O=64 H=128 Y=7.  NBSEQ=5888 = 184 blocks x 32 seqs.
// kernPrep: pack W (bf16, MFMA-A fragment order, gate-grouped rows) + gwt.
// kernA   : per-(b,d) graph stage -> adj (out0) + zin packed bf16 hi/lo in
//           MFMA-B layout [step][blk184][k8 0..8][hi/lo][seq32][8e].
// kernB   : 2-layer LSTM via mfma_f32_16x16x32_bf16, U split hi+lo, W single
//           bf16 streamed from L2; gates of a channel live in one lane.
// R6: persistent per-thread state (c0[8], c1[8], x2r[8]) moved to LDS slots
//     ([slot][t] conflict-free). R2-R5 showed arch-VGPR cap pinned at 128
//     regardless of hints; these 24 long-lived regs were the spill set
//     (WRITE 85MB = ~6 f32 spilled/reloaded per thread-step). LDS now 108KB,
//     still 1 block/CU (grid 184 <= 256 CUs).
// ---------------------------------------------------------------------------

#define DB 256
#define DD 28
#define DN 23
#define DF 128
#define DO 64
#define DH 128
#define DY 7
#define NBSEQ (DN*DB)
#define ADJSZ (DB*DD*DN*DN)
#define GBLK 184

// workspace byte offsets
#define ZB_BYTES  47480832u            // 28*184*576*16
#define WB0_OFF   47480832u            // 7*32*64*8*2  = 229376
#define WB1_OFF   47710208u            // 8*32*64*8*2  = 262144
#define GWT_OFFB  47972352u            // 8192 f32

using v8bf  = __attribute__((ext_vector_type(8))) __bf16;
using f32x4 = __attribute__((ext_vector_type(4))) float;
using u32x4 = __attribute__((ext_vector_type(4))) unsigned int;

__device__ __forceinline__ float fsig(float x)  { return 1.f/(1.f+__expf(-x)); }
__device__ __forceinline__ float ftanh(float x) { return 1.f - 2.f/(__expf(2.f*x)+1.f); }

__device__ __forceinline__ unsigned short f2bf(float f){
    unsigned u = __builtin_bit_cast(unsigned, f);
    return (unsigned short)((u + 0x7FFFu + ((u>>16)&1u)) >> 16);
}
__device__ __forceinline__ float bf2f(unsigned short b){
    return __builtin_bit_cast(float, (unsigned)b << 16);
}
__device__ __forceinline__ uint4 ntload4(const uint4* p){
    u32x4 v = __builtin_nontemporal_load((const u32x4*)p);
    return *(uint4*)&v;
}

#define FMA4(xv, wv, a) fmaf((xv).w,(wv).w, fmaf((xv).z,(wv).z, fmaf((xv).y,(wv).y, fmaf((xv).x,(wv).x,(a)))))
#define MFMA_(acc_, A_, B_) acc_ = __builtin_amdgcn_mfma_f32_16x16x32_bf16(A_, B_, acc_, 0, 0, 0)

// ---------------------------------------------------------------------------
// Prep. Wb[kt][mt][lane][e]: A-frag row rit=lane&15 -> (localj=rit>>2, g=rit&3),
// orig row r = g*128 + mt*4 + localj; k = kt*32 + (lane>>4)*8 + e.
// L0 cols: k<65 -> wih0 ; 72<=k<200 -> whh0[k-72] ; else 0.  (x padded to 72)
// L1 cols: k<128 -> wih1 ; else whh1[k-128].
// ---------------------------------------------------------------------------
__global__ __launch_bounds__(256) void kernPrep(
    const float* __restrict__ wih0, const float* __restrict__ whh0,
    const float* __restrict__ wih1, const float* __restrict__ whh1,
    const float* __restrict__ gcn_w,
    unsigned short* __restrict__ wb0, unsigned short* __restrict__ wb1,
    float* __restrict__ gwt)
{
    int idx = blockIdx.x*256 + threadIdx.x;
    if (idx < 114688){
        int e = idx&7, l = (idx>>3)&63, mt = (idx>>9)&31, kt = idx>>14;
        int rit = l&15, lj = rit>>2, g = rit&3;
        int r = g*128 + mt*4 + lj;
        int k = kt*32 + (l>>4)*8 + e;
        float v = 0.f;
        if (k < 65)                 v = wih0[r*65 + k];
        else if (k >= 72 && k < 200) v = whh0[r*128 + (k-72)];
        wb0[idx] = f2bf(v);
        return;
    }
    idx -= 114688;
    if (idx < 131072){
        int e = idx&7, l = (idx>>3)&63, mt = (idx>>9)&31, kt = idx>>14;
        int rit = l&15, lj = rit>>2, g = rit&3;
        int r = g*128 + mt*4 + lj;
        int k = kt*32 + (l>>4)*8 + e;
        float v = (k < 128) ? wih1[r*128 + k] : whh1[r*128 + (k-128)];
        wb1[idx] = f2bf(v);
        return;
    }
    idx -= 131072;
    if (idx < 8192){
        int o = idx >> 7, f = idx & 127;
        gwt[idx] = gcn_w[f*DO + o];     // gwt[o][f]
    }
}

// ---------------------------------------------------------------------------
// Kernel A: per-(b,d) graph stage.  grid = 7168, block = 256.
// ---------------------------------------------------------------------------
__global__ __launch_bounds__(256) void kernA(
    const float* __restrict__ x, const float* __restrict__ adj_real,
    const float* __restrict__ infection, const int* __restrict__ day_order,
    const float* __restrict__ w1, const float* __restrict__ b1,
    const float* __restrict__ w2, const float* __restrict__ b2,
    const float* __restrict__ glp, const float* __restrict__ vvec,
    const float* __restrict__ gwt,
    float* __restrict__ out_adj, uint4* __restrict__ zb4)
{
    const int bd = blockIdx.x;
    const int b  = bd / DD;
    const int d  = bd - b*DD;
    const int t  = threadIdx.x;

    __shared__ float sm[11776];
    const int XS=0, N1=3036, N2=6072, S12=9108, ADJ=9660, XW=10212,
              DEG=11684, DINV=11707, FACT=11730, INFS=11753;
    const int XWP = N1;   // alias (A7 partials; dead before GC reuse)
    const int GC  = N1;   // alias (A8 gcn output)

    const float* xg = x + (size_t)bd * (DN*DF);
    for (int p = t; p < DN*DF; p += 256) {
        int n = p >> 7, f = p & 127;
        sm[XS + n*132 + f] = xg[p];
    }
    if (t < DN) {
        float vv = vvec[t];
        sm[FACT + t] = __expf(vv*vv*(float)day_order[b]);
        sm[INFS + t] = infection[(size_t)bd*DN + t];
    }
    __syncthreads();

    // A2: n1/n2
    {
        const int mat = t >> 7, fo = t & 127;
        const float* wr = (mat ? w2 : w1) + fo*DF;
        const float bias = (mat ? b2 : b1)[fo];
        float acc[DN];
        #pragma unroll
        for (int n=0;n<DN;n++) acc[n]=0.f;
        float4 w4 = *(const float4*)wr;
        for (int k4=0;k4<32;k4++){
            float4 wn = w4;
            if (k4 < 31) wn = *(const float4*)(wr + 4*(k4+1));
            #pragma unroll
            for (int n=0;n<DN;n++){
                float4 xv = *(const float4*)&sm[XS + n*132 + 4*k4];
                acc[n] = FMA4(xv, w4, acc[n]);
            }
            w4 = wn;
        }
        const int dst = mat ? N2 : N1;
        #pragma unroll
        for (int n=0;n<DN;n++) sm[dst + n*132 + fo] = ftanh(acc[n]+bias);
    }
    __syncthreads();

    // A3: s12 + deg
    if (t < DN) {
        const float* ar = adj_real + (size_t)bd*(DN*DN) + t*DN;
        float s = 0.f;
        for (int m=0;m<DN;m++) s += ar[m];
        sm[DEG+t] = s;
    }
    for (int p=t; p<DN*DN; p+=256){
        int i = p/DN, j = p - i*DN;
        float a = 0.f;
        for (int k4=0;k4<32;k4++){
            float4 av = *(const float4*)&sm[N1 + i*132 + 4*k4];
            float4 bv = *(const float4*)&sm[N2 + j*132 + 4*k4];
            a = FMA4(av, bv, a);
        }
        sm[S12 + i*24 + j] = a;
    }
    __syncthreads();

    // A4: adj
    for (int p=t; p<DN*DN; p+=256){
        int i=p/DN, j=p-i*DN;
        float al  = fmaxf(ftanh(sm[S12+i*24+j]-sm[S12+j*24+i]), 0.f);
        float md  = fsig(glp[i*DN+j]*sm[DEG+i]*sm[DEG+j]);
        float arv = adj_real[(size_t)bd*(DN*DN) + p];
        float adjv = al + md*arv;
        __builtin_nontemporal_store(adjv, &out_adj[(size_t)bd*(DN*DN) + p]);
        sm[ADJ + i*24 + j] = adjv + (i==j ? 1.f : 0.f);
    }
    __syncthreads();

    if (t<DN){
        float rs=0.f;
        for (int jj=0;jj<DN;jj++) rs += sm[ADJ+t*24+jj];
        sm[DINV+t] = rsqrtf(rs);
    }
    __syncthreads();
    for (int p=t;p<DN*DN;p+=256){
        int i=p/DN, j=p-i*DN;
        sm[ADJ+i*24+j] *= sm[DINV+i]*sm[DINV+j];
    }
    __syncthreads();

    // A7: xw = x @ gcn_w (k split 4 ways)
    {
        const int o = t & 63, q = t >> 6;
        float acc[DN];
        #pragma unroll
        for (int n=0;n<DN;n++) acc[n]=0.f;
        const float* gw = gwt + o*DF + q*32;
        for (int k4=0;k4<8;k4++){
            float4 w4 = *(const float4*)(gw + 4*k4);
            #pragma unroll
            for (int n=0;n<DN;n++){
                float4 xv = *(const float4*)&sm[XS + n*132 + q*32 + 4*k4];
                acc[n] = FMA4(xv, w4, acc[n]);
            }
        }
        #pragma unroll
        for (int n=0;n<DN;n++) sm[XWP + (q*DN+n)*64 + o] = acc[n];
    }
    __syncthreads();
    for (int p=t;p<DN*64;p+=256){
        int n=p>>6, o=p&63;
        sm[XW+p] = sm[XWP + n*64 + o] + sm[XWP + (DN+n)*64 + o]
                 + sm[XWP + (2*DN+n)*64 + o] + sm[XWP + (3*DN+n)*64 + o];
    }
    __syncthreads();

    // A8: gcn -> GC (factor applied)
    for (int p=t;p<DN*64;p+=256){
        int n=p>>6, o=p&63;
        float a=0.f;
        #pragma unroll
        for (int m=0;m<DN;m++) a = fmaf(sm[ADJ+n*24+m], sm[XW+m*64+o], a);
        sm[GC + p] = fmaxf(a,0.f)*sm[FACT+n];
    }
    __syncthreads();

    // pack: per (n, k8 0..8, hi/lo): 8 elems -> one uint4
    for (int p=t; p<DN*18; p+=256){
        int n = p/18, r = p - n*18, k8 = r>>1, hsel = r&1;
        __align__(16) unsigned short ob[8];
        #pragma unroll
        for (int e=0;e<8;e++){
            int k = k8*8+e;
            float v = (k<64) ? sm[GC + n*64 + k] : ((k==64) ? sm[INFS+n] : 0.f);
            unsigned short hb = f2bf(v);
            ob[e] = hsel ? f2bf(v - bf2f(hb)) : hb;
        }
        int gseq = n*DB + b;
        int blkz = gseq >> 5, seq = gseq & 31;
        zb4[(size_t)(d*GBLK + blkz)*576 + hsel*288 + k8*32 + seq] = *(const uint4*)ob;
    }
}

// ---------------------------------------------------------------------------
// Kernel B: MFMA LSTM.  grid=184, block=512 (8 waves).  Wave w: M-tiles 4w..4w+3.
// Lane: lhi=l>>4 -> local channel, llo=l&15 -> seq within N-tile.
// acc[mi][nt] f32x4: regs = gates (i,f,g,o) of channel j=16w+mi*4+lhi, seq=nt*16+llo.
// Persistent state (c0,c1,x2sum) + biases live in LDS -> minimal arch-VGPR
// live-range; only the MFMA working set stays in registers.
// ---------------------------------------------------------------------------
#define U0HI 0
#define U0LO 14336
#define U1HI 28672
#define U1LO 45056
#define FCWO 61440
#define INFCO 61956
#define BIAS0 62084
#define BIAS1 64132
#define X2S   66192        // 288*8 f32, layout [e][288]
#define C0S   75408        // 8 slots * 512 f32, layout [slot][t]
#define C1S   91792        // 8 slots * 512 f32
// end 108176

__global__ __attribute__((amdgpu_flat_work_group_size(512,512), amdgpu_waves_per_eu(2,2)))
void kernB(
    const uint4* __restrict__ zb4, const v8bf* __restrict__ w0p, const v8bf* __restrict__ w1p,
    const float* __restrict__ b0g, const float* __restrict__ b1g,
    const float* __restrict__ infection, const float* __restrict__ fcw,
    const float* __restrict__ fcb, float* __restrict__ outy)
{
    const int t = threadIdx.x, blk = blockIdx.x;
    const int w = t>>6, l = t&63;
    const int lhi = l>>4, llo = l&15;
    __shared__ __align__(16) unsigned char smraw[108176];
    char* smb = (char*)smraw;

    // zero U0/U1 (61440 B) + X2S/C0S/C1S (66192..108176)
    {
        uint4 z; z.x=z.y=z.z=z.w=0u;
        for (int i = t; i < 61440/16; i += 512) ((uint4*)smraw)[i] = z;
        for (int i = t; i < (108176-66192)/16; i += 512) ((uint4*)(smb+66192))[i] = z;
    }
    if (t < 129) ((float*)(smb+FCWO))[t] = (t<128) ? fcw[t] : fcb[0];
    if (t < 32){
        int gseq = blk*32 + t, n = gseq>>8, bb = gseq&255;
        float a = 0.f;
        for (int dd=0; dd<DD; dd++)
            a = fmaf(fcw[128+dd], infection[((size_t)bb*DD+dd)*DN+n], a);
        ((float*)(smb+INFCO))[t] = a;
    }
    ((float*)(smb+BIAS0))[t] = b0g[t];
    ((float*)(smb+BIAS1))[t] = b1g[t];
    __syncthreads();

    // stage step 0 (x part of U0): unit u = w*72 + i, hi units 0..287, lo 288..575
    {
        const uint4* src = zb4 + (size_t)blk*576;
        int u = w*72 + l;
        uint4 a0 = ntload4(src + u);
        int d0 = (u<288) ? u*16 : (U0LO + (u-288)*16);
        *(uint4*)(smb + d0) = a0;
        if (l < 8){
            int u2 = u + 64;
            uint4 a1 = ntload4(src + u2);
            int d1 = (u2<288) ? u2*16 : (U0LO + (u2-288)*16);
            *(uint4*)(smb + d1) = a1;
        }
    }
    __syncthreads();

    const float* bias0L = (const float*)(smb+BIAS0);
    const float* bias1L = (const float*)(smb+BIAS1);

    for (int step = 0; step < DD + DY; ++step){
        // ---- running input mean (encoder) / build decoder input (step 28)
        if (step < DD){
            if (t < 288){
                uint4 hv = *(const uint4*)(smb + U0HI + t*16);
                uint4 lv = *(const uint4*)(smb + U0LO + t*16);
                const unsigned short* hp = (const unsigned short*)&hv;
                const unsigned short* lp = (const unsigned short*)&lv;
                float* xs = (float*)(smb + X2S);
                #pragma unroll
                for (int e=0;e<8;e++) xs[e*288+t] += bf2f(hp[e]) + bf2f(lp[e]);
            }
        } else if (step == DD){
            if (t < 288){
                const float* xs = (const float*)(smb + X2S);
                __align__(16) unsigned short hb8[8], lb8[8];
                #pragma unroll
                for (int e=0;e<8;e++){
                    float v = xs[e*288+t] * (1.f/(float)DD);
                    unsigned short h = f2bf(v);
                    hb8[e] = h;
                    lb8[e] = f2bf(v - bf2f(h));
                }
                *(uint4*)(smb + U0HI + t*16) = *(const uint4*)hb8;
                *(uint4*)(smb + U0LO + t*16) = *(const uint4*)lb8;
            }
            __syncthreads();
        }

        // ---------------- layer 0: G = W0 @ [x|h0], 7 k-tiles ----------------
        {
            f32x4 acc[4][2];
            #pragma unroll
            for (int mi=0;mi<4;mi++){
                int j = 16*w + mi*4 + lhi;
                f32x4 a;
                a[0]=bias0L[j]; a[1]=bias0L[128+j]; a[2]=bias0L[256+j]; a[3]=bias0L[384+j];
                acc[mi][0] = a; acc[mi][1] = a;
            }
            #pragma unroll
            for (int kt=0; kt<7; ++kt){
                const v8bf* wrow = w0p + (size_t)(kt*32 + w*4)*64 + l;
                v8bf A0 = wrow[0], A1 = wrow[64], A2 = wrow[128], A3 = wrow[192];
                int bu = (kt*4 + lhi)*32 + llo;
                v8bf BH0 = *(const v8bf*)(smb + U0HI + bu*16);
                v8bf BH1 = *(const v8bf*)(smb + U0HI + (bu+16)*16);
                v8bf BL0 = *(const v8bf*)(smb + U0LO + bu*16);
                v8bf BL1 = *(const v8bf*)(smb + U0LO + (bu+16)*16);
                MFMA_(acc[0][0], A0, BH0); MFMA_(acc[0][0], A0, BL0);
                MFMA_(acc[1][0], A1, BH0); MFMA_(acc[1][0], A1, BL0);
                MFMA_(acc[2][0], A2, BH0); MFMA_(acc[2][0], A2, BL0);
                MFMA_(acc[3][0], A3, BH0); MFMA_(acc[3][0], A3, BL0);
                MFMA_(acc[0][1], A0, BH1); MFMA_(acc[0][1], A0, BL1);
                MFMA_(acc[1][1], A1, BH1); MFMA_(acc[1][1], A1, BL1);
                MFMA_(acc[2][1], A2, BH1); MFMA_(acc[2][1], A2, BL1);
                MFMA_(acc[3][1], A3, BH1); MFMA_(acc[3][1], A3, BL1);
            }
            __syncthreads();   // B2: all U0 reads done

            // issue next-step x loads (written to LDS after L1)
            uint4 sv0, sv1; sv0.x=sv0.y=sv0.z=sv0.w=0u; sv1 = sv0;
            const bool do_stage = (step + 1 < DD);
            if (do_stage){
                const uint4* src = zb4 + (size_t)((step+1)*GBLK + blk)*576;
                sv0 = ntload4(src + w*72 + l);
                if (l < 8) sv1 = ntload4(src + w*72 + 64 + l);
            }

            // activation L0 + h0 writes (U0 h-region + U1 h0-region)
            #pragma unroll
            for (int mi=0;mi<4;mi++){
                int j = 16*w + mi*4 + lhi;
                int j8 = j>>3, je = j&7;
                #pragma unroll
                for (int nt=0;nt<2;nt++){
                    float* cslot = (float*)(smb + C0S) + (mi*2+nt)*512 + t;
                    f32x4 a = acc[mi][nt];
                    float ii = fsig(a[0]), ff = fsig(a[1]), gg = ftanh(a[2]), oo = fsig(a[3]);
                    float c = ff*cslot[0] + ii*gg;
                    cslot[0] = c;
                    float h = oo*ftanh(c);
                    unsigned short hb = f2bf(h);
                    unsigned short lb = f2bf(h - bf2f(hb));
                    int seq = nt*16 + llo;
                    ((unsigned short*)(smb+U0HI))[((9+j8)*32+seq)*8 + je] = hb;
                    ((unsigned short*)(smb+U0LO))[((9+j8)*32+seq)*8 + je] = lb;
                    ((unsigned short*)(smb+U1HI))[(j8*32+seq)*8 + je]     = hb;
                    ((unsigned short*)(smb+U1LO))[(j8*32+seq)*8 + je]     = lb;
                }
            }
            __syncthreads();   // B3: h0 visible

            // ---------------- layer 1: G = W1 @ [h0|h1], 8 k-tiles ----------------
            f32x4 acc1[4][2];
            #pragma unroll
            for (int mi=0;mi<4;mi++){
                int j = 16*w + mi*4 + lhi;
                f32x4 a;
                a[0]=bias1L[j]; a[1]=bias1L[128+j]; a[2]=bias1L[256+j]; a[3]=bias1L[384+j];
                acc1[mi][0] = a; acc1[mi][1] = a;
            }
            #pragma unroll
            for (int kt=0; kt<8; ++kt){
                const v8bf* wrow = w1p + (size_t)(kt*32 + w*4)*64 + l;
                v8bf A0 = wrow[0], A1 = wrow[64], A2 = wrow[128], A3 = wrow[192];
                int bu = (kt*4 + lhi)*32 + llo;
                v8bf BH0 = *(const v8bf*)(smb + U1HI + bu*16);
                v8bf BH1 = *(const v8bf*)(smb + U1HI + (bu+16)*16);
                v8bf BL0 = *(const v8bf*)(smb + U1LO + bu*16);
                v8bf BL1 = *(const v8bf*)(smb + U1LO + (bu+16)*16);
                MFMA_(acc1[0][0], A0, BH0); MFMA_(acc1[0][0], A0, BL0);
                MFMA_(acc1[1][0], A1, BH0); MFMA_(acc1[1][0], A1, BL0);
                MFMA_(acc1[2][0], A2, BH0); MFMA_(acc1[2][0], A2, BL0);
                MFMA_(acc1[3][0], A3, BH0); MFMA_(acc1[3][0], A3, BL0);
                MFMA_(acc1[0][1], A0, BH1); MFMA_(acc1[0][1], A0, BL1);
                MFMA_(acc1[1][1], A1, BH1); MFMA_(acc1[1][1], A1, BL1);
                MFMA_(acc1[2][1], A2, BH1); MFMA_(acc1[2][1], A2, BL1);
                MFMA_(acc1[3][1], A3, BH1); MFMA_(acc1[3][1], A3, BL1);
            }
            __syncthreads();   // B4: all U1 reads done

            if (do_stage){
                int u = w*72 + l;
                int d0 = (u<288) ? u*16 : (U0LO + (u-288)*16);
                *(uint4*)(smb + d0) = sv0;
                if (l < 8){
                    int u2 = u + 64;
                    int d1 = (u2<288) ? u2*16 : (U0LO + (u2-288)*16);
                    *(uint4*)(smb + d1) = sv1;
                }
            }

            // activation L1 + h1 writes
            #pragma unroll
            for (int mi=0;mi<4;mi++){
                int j = 16*w + mi*4 + lhi;
                int j8 = j>>3, je = j&7;
                #pragma unroll
                for (int nt=0;nt<2;nt++){
                    float* cslot = (float*)(smb + C1S) + (mi*2+nt)*512 + t;
                    f32x4 a = acc1[mi][nt];
                    float ii = fsig(a[0]), ff = fsig(a[1]), gg = ftanh(a[2]), oo = fsig(a[3]);
                    float c = ff*cslot[0] + ii*gg;
                    cslot[0] = c;
                    float h = oo*ftanh(c);
                    unsigned short hb = f2bf(h);
                    unsigned short lb = f2bf(h - bf2f(hb));
                    int seq = nt*16 + llo;
                    ((unsigned short*)(smb+U1HI))[((16+j8)*32+seq)*8 + je] = hb;
                    ((unsigned short*)(smb+U1LO))[((16+j8)*32+seq)*8 + je] = lb;
                }
            }
        }

        // ---- decoder FC
        if (step >= DD){
            __syncthreads();   // h1 visible
            if (t < 256){
                int seq = t>>3, l8 = t&7;
                const unsigned short* uh = (const unsigned short*)(smb+U1HI);
                const unsigned short* ul = (const unsigned short*)(smb+U1LO);
                const float* fw = (const float*)(smb+FCWO);
                float a = 0.f;
                #pragma unroll
                for (int half=0; half<2; ++half){
                    int k8 = 16 + l8*2 + half;
                    int base = (k8*32 + seq)*8;
                    #pragma unroll
                    for (int e=0;e<8;e++){
                        int j = l8*16 + half*8 + e;
                        a = fmaf(fw[j], bf2f(uh[base+e]) + bf2f(ul[base+e]), a);
                    }
                }
                a += __shfl_down(a, 4, 8);
                a += __shfl_down(a, 2, 8);
                a += __shfl_down(a, 1, 8);
                if (l8 == 0){
                    int gseq = blk*32 + seq, n = gseq>>8, bb = gseq&255;
                    float yv = fmaxf(a + ((const float*)(smb+INFCO))[seq] + fw[128], 0.f);
                    __builtin_nontemporal_store(yv, &outy[((size_t)bb*DY + (step-DD))*DN + n]);
                }
            }
        }
        __syncthreads();   // close step (staging writes / FC reads before next iter)
    }
}

// ---------------------------------------------------------------------------
extern "C" void kernel_launch(void* const* d_in, const int* in_sizes, int n_in,
                              void* d_out, int out_size, void* d_ws, size_t ws_size,
                              hipStream_t stream)
{
    const float* x         = (const float*)d_in[0];
    const float* adj_real  = (const float*)d_in[1];
    const float* infection = (const float*)d_in[2];
    const int*   day_order = (const int*)  d_in[3];
    const float* gl_w1     = (const float*)d_in[4];
    const float* gl_b1     = (const float*)d_in[5];
    const float* gl_w2     = (const float*)d_in[6];
    const float* gl_b2     = (const float*)d_in[7];
    const float* glp       = (const float*)d_in[8];
    const float* gcn_w     = (const float*)d_in[9];
    const float* vvec      = (const float*)d_in[10];
    const float* wih0      = (const float*)d_in[11];
    const float* whh0      = (const float*)d_in[12];
    const float* b0        = (const float*)d_in[13];
    const float* wih1      = (const float*)d_in[14];
    const float* whh1      = (const float*)d_in[15];
    const float* b1        = (const float*)d_in[16];
    const float* fcw       = (const float*)d_in[17];
    const float* fcb       = (const float*)d_in[18];

    uint8_t* wsb = (uint8_t*)d_ws;
    unsigned short* zb  = (unsigned short*)(wsb);
    unsigned short* wb0 = (unsigned short*)(wsb + WB0_OFF);
    unsigned short* wb1 = (unsigned short*)(wsb + WB1_OFF);
    float*          gwt = (float*)(wsb + GWT_OFFB);
    float* out_adj = (float*)d_out;
    float* out_y   = out_adj + ADJSZ;

    kernPrep<<<dim3(992), dim3(256), 0, stream>>>(wih0, whh0, wih1, whh1, gcn_w,
                                                  wb0, wb1, gwt);
    kernA<<<dim3(DB*DD), dim3(256), 0, stream>>>(x, adj_real, infection, day_order,
                                                 gl_w1, gl_b1, gl_w2, gl_b2, glp,
                                                 vvec, gwt, out_adj, (uint4*)zb);
    kernB<<<dim3(GBLK), dim3(512), 0, stream>>>((const uint4*)zb, (const v8bf*)wb0,
                                                (const v8bf*)wb1, b0, b1, infection,
                                                fcw, fcb, out_y);
}